// Round 19
// baseline (676.633 us; speedup 1.0000x reference)
//
#include <hip/hip_runtime.h>
#include <math.h>

typedef unsigned short u16;
typedef __attribute__((ext_vector_type(8))) short short8;
typedef __attribute__((ext_vector_type(4))) float floatx4;
typedef __attribute__((ext_vector_type(4))) unsigned short ushort4v;
typedef __attribute__((ext_vector_type(8))) unsigned short ushort8v;

#define DEV static __device__ __forceinline__

DEV u16 f2b(float f) {
  unsigned u = __builtin_bit_cast(unsigned, f);
  u += 0x7fffu + ((u >> 16) & 1u);
  return (u16)(u >> 16);
}
DEV float b2f(u16 h) { return __builtin_bit_cast(float, ((unsigned)h) << 16); }

DEV void gld16(const u16* g, u16* l) {
  __builtin_amdgcn_global_load_lds((__attribute__((address_space(1))) void*)(g),
                                   (__attribute__((address_space(3))) void*)(l), 16, 0, 0);
}

// ---------------- K1: merged prep: token-shift mixes + LoRA transposes + weight casts ----------------
__global__ __launch_bounds__(256) void prep(
    const float* __restrict__ x,
    const float* __restrict__ cr, const float* __restrict__ ck,
    const float* __restrict__ cv, const float* __restrict__ cw,
    const float* __restrict__ ca, const float* __restrict__ cg,
    u16* __restrict__ oxr, u16* __restrict__ oxk, u16* __restrict__ oxv,
    u16* __restrict__ oxw, u16* __restrict__ oxa, u16* __restrict__ oxg,
    const float* __restrict__ w1, const float* __restrict__ a1,
    const float* __restrict__ v1, const float* __restrict__ g1,
    const float* __restrict__ w2, const float* __restrict__ a2,
    const float* __restrict__ v2, const float* __restrict__ g2,
    u16* __restrict__ w1T, u16* __restrict__ a1T, u16* __restrict__ v1T,
    u16* __restrict__ g1T, u16* __restrict__ w2T, u16* __restrict__ a2T,
    u16* __restrict__ v2T, u16* __restrict__ g2T,
    const float* __restrict__ Wr, const float* __restrict__ Wk,
    const float* __restrict__ Wv, const float* __restrict__ Wo,
    u16* __restrict__ Wr16, u16* __restrict__ Wk16,
    u16* __restrict__ Wv16, u16* __restrict__ Wo16)
{
  const int bid = blockIdx.x;
  if (bid < 8192) {
    const long idx = (long)bid * 256 + threadIdx.x;
    const long row = idx >> 8;
    const int c8 = (int)(idx & 255) << 3;
    const long off = (row << 11) + c8;
    const floatx4 xa_ = *(const floatx4*)(x + off);
    const floatx4 xb_ = *(const floatx4*)(x + off + 4);
    floatx4 pa = (floatx4)0.f, pb = (floatx4)0.f;
    if ((row & 4095) != 0) {
      pa = *(const floatx4*)(x + off - 2048);
      pb = *(const floatx4*)(x + off - 2044);
    }
    floatx4 da, db;
#pragma unroll
    for (int i = 0; i < 4; ++i) { da[i] = pa[i] - xa_[i]; db[i] = pb[i] - xb_[i]; }
#define EMIT(cp, op) {                                                         \
    const floatx4 c0 = *(const floatx4*)(cp + c8);                             \
    const floatx4 c1 = *(const floatx4*)(cp + c8 + 4);                         \
    ushort8v o;                                                                \
    _Pragma("unroll")                                                          \
    for (int i = 0; i < 4; ++i) {                                              \
      o[i]     = f2b(xa_[i] + da[i] * c0[i]);                                  \
      o[4 + i] = f2b(xb_[i] + db[i] * c1[i]);                                  \
    }                                                                          \
    *(ushort8v*)(op + off) = o; }
    EMIT(cr, oxr); EMIT(ck, oxk); EMIT(cv, oxv);
    EMIT(cw, oxw); EMIT(ca, oxa); EMIT(cg, oxg);
#undef EMIT
    return;
  }
  const int tb = bid - 8192;
  const int by = tb >> 11;
  const long idx = (long)(tb & 2047) * 256 + threadIdx.x;
  if (by >= 8) {
    const float* s; u16* d;
    switch (by) {
      case 8:  s = Wr; d = Wr16; break;
      case 9:  s = Wk; d = Wk16; break;
      case 10: s = Wv; d = Wv16; break;
      default: s = Wo; d = Wo16; break;
    }
    const long i = idx * 8;
    const float4 a = *(const float4*)(s + i);
    const float4 b = *(const float4*)(s + i + 4);
    ushort4v lo = { f2b(a.x), f2b(a.y), f2b(a.z), f2b(a.w) };
    ushort4v hi = { f2b(b.x), f2b(b.y), f2b(b.z), f2b(b.w) };
    *(ushort4v*)(d + i) = lo;
    *(ushort4v*)(d + i + 4) = hi;
    return;
  }
  const float* src; u16* dst; int sk, sn, dn, dk;
  switch (by) {
    case 0: src = w1; dst = w1T; sk = 2048; sn = 128; dn = 128;  dk = 2048; break;
    case 1: src = a1; dst = a1T; sk = 2048; sn = 128; dn = 128;  dk = 2048; break;
    case 2: src = v1; dst = v1T; sk = 2048; sn = 64;  dn = 128;  dk = 2048; break;
    case 3: src = g1; dst = g1T; sk = 2048; sn = 224; dn = 256;  dk = 2048; break;
    case 4: src = w2; dst = w2T; sk = 128;  sn = 2048; dn = 2048; dk = 128; break;
    case 5: src = a2; dst = a2T; sk = 128;  sn = 2048; dn = 2048; dk = 128; break;
    case 6: src = v2; dst = v2T; sk = 64;   sn = 2048; dn = 2048; dk = 128; break;
    default:src = g2; dst = g2T; sk = 224;  sn = 2048; dn = 2048; dk = 256; break;
  }
  const long total = (long)dn * dk;
  if (idx >= total) return;
  const int n = (int)(idx / dk), k = (int)(idx % dk);
  float v = 0.f;
  if (k < sk && n < sn) v = src[(long)k * sn + n];
  dst[idx] = f2b(v);
}

// ---------------- shared 128x128 GEMM body (m97 structure) ----------------
#define GEMM128_BODY(Abase, Bbase, K)                                          \
  floatx4 acc[4][4];                                                           \
  _Pragma("unroll")                                                            \
  for (int i = 0; i < 4; ++i)                                                  \
    _Pragma("unroll")                                                          \
    for (int jq = 0; jq < 4; ++jq) acc[i][jq] = (floatx4)0.f;                  \
  const int nK = (K) >> 6;                                                     \
  for (int kt = 0; kt < nK; ++kt) {                                            \
    const int k0 = kt << 6;                                                    \
    __syncthreads();                                                           \
    _Pragma("unroll")                                                          \
    for (int i = 0; i < 4; ++i) {                                              \
      const int c = i * 256 + tid;                                             \
      const int row = c >> 3;                                                  \
      const int sch = (c & 7) ^ (row & 7);                                     \
      const long goff = (long)row * (K) + k0 + sch * 8;                        \
      const int lbase = (i * 256 + wave * 64) * 8;                             \
      gld16((Abase) + goff, &sA[lbase]);                                       \
      gld16((Bbase) + goff, &sB[lbase]);                                       \
    }                                                                          \
    asm volatile("s_waitcnt vmcnt(0)" ::: "memory");                           \
    __syncthreads();                                                           \
    _Pragma("unroll")                                                          \
    for (int ks = 0; ks < 2; ++ks) {                                           \
      short8 af[4], bfr[4];                                                    \
      _Pragma("unroll")                                                        \
      for (int mi = 0; mi < 4; ++mi) {                                         \
        const int row = wm * 64 + mi * 16 + lrow;                              \
        const int ch = (ks * 4 + lkg) ^ (row & 7);                             \
        af[mi] = *(const short8*)&sA[row * 64 + ch * 8];                       \
      }                                                                        \
      _Pragma("unroll")                                                        \
      for (int ni = 0; ni < 4; ++ni) {                                         \
        const int row = wn * 64 + ni * 16 + lrow;                              \
        const int ch = (ks * 4 + lkg) ^ (row & 7);                             \
        bfr[ni] = *(const short8*)&sB[row * 64 + ch * 8];                      \
      }                                                                        \
      _Pragma("unroll")                                                        \
      for (int mi = 0; mi < 4; ++mi)                                           \
        _Pragma("unroll")                                                      \
        for (int ni = 0; ni < 4; ++ni)                                         \
          acc[mi][ni] = __builtin_amdgcn_mfma_f32_16x16x32_bf16(af[mi], bfr[ni], acc[mi][ni], 0, 0, 0); \
    }                                                                          \
  }

// ---------------- merged LoRA stage-1: 4 jobs, one launch ----------------
__global__ __launch_bounds__(256, 2) void gemm_s1(
    const u16* __restrict__ xw, const u16* __restrict__ w1T, u16* __restrict__ hw,
    const u16* __restrict__ xa, const u16* __restrict__ a1T, u16* __restrict__ ha,
    const u16* __restrict__ xv, const u16* __restrict__ v1T, u16* __restrict__ hv,
    const u16* __restrict__ xg, const u16* __restrict__ g1T, u16* __restrict__ hg)
{
  __shared__ __align__(16) u16 sA[128 * 64];
  __shared__ __align__(16) u16 sB[128 * 64];
  const int bid = blockIdx.x;
  const int jid = (bid < 64) ? 0 : (bid < 128) ? 1 : (bid < 192) ? 2 : 3;
  const u16* A = (jid == 0) ? xw : (jid == 1) ? xa : (jid == 2) ? xv : xg;
  const u16* B = (jid == 0) ? w1T : (jid == 1) ? a1T : (jid == 2) ? v1T : g1T;
  u16* Cv = (jid == 0) ? hw : (jid == 1) ? ha : (jid == 2) ? hv : hg;
  const int N = (jid == 3) ? 256 : 128;
  const int lb = bid - ((jid == 0) ? 0 : (jid == 1) ? 64 : (jid == 2) ? 128 : 192);
  const int tid = threadIdx.x;
  const int wave = tid >> 6, lane = tid & 63;
  const int lrow = lane & 15, lkg = lane >> 4;
  const int wm = wave >> 1, wn = wave & 1;
  const int nbn = N >> 7;
  const int bm = lb / nbn, bn = lb % nbn;
  const u16* Abase = A + (long)bm * 128 * 2048;
  const u16* Bbase = B + (long)bn * 128 * 2048;

  GEMM128_BODY(Abase, Bbase, 2048)

  const int row0 = bm * 128 + wm * 64 + lkg * 4;
  const int col0 = bn * 128 + wn * 64 + lrow;
#pragma unroll
  for (int mi = 0; mi < 4; ++mi)
#pragma unroll
    for (int ni = 0; ni < 4; ++ni) {
      const int col = col0 + ni * 16;
#pragma unroll
      for (int r = 0; r < 4; ++r) {
        const long o = (long)(row0 + mi * 16 + r) * N + col;
        float v = acc[mi][ni][r];
        if (jid == 0) v = tanhf(v);
        else if (jid == 3) v = 1.f / (1.f + expf(-v));
        Cv[o] = f2b(v);
      }
    }
}

// ---------------- merged LoRA stage-2: 4 jobs x 1024 blocks ----------------
__global__ __launch_bounds__(256, 2) void gemm_s2(
    const u16* __restrict__ hw, const u16* __restrict__ w2T, float* __restrict__ wsec, const float* __restrict__ w0,
    const u16* __restrict__ ha, const u16* __restrict__ a2T, float* __restrict__ asec, const float* __restrict__ a0,
    const u16* __restrict__ hv, const u16* __restrict__ v2T, u16* __restrict__ vs, const float* __restrict__ v0,
    const u16* __restrict__ hg, const u16* __restrict__ g2T, u16* __restrict__ gb)
{
  __shared__ __align__(16) u16 sA[128 * 64];
  __shared__ __align__(16) u16 sB[128 * 64];
  const int jid = blockIdx.x >> 10;
  const int lb = blockIdx.x & 1023;
  const u16* A = (jid == 0) ? hw : (jid == 1) ? ha : (jid == 2) ? hv : hg;
  const u16* B = (jid == 0) ? w2T : (jid == 1) ? a2T : (jid == 2) ? v2T : g2T;
  const float* bias = (jid == 0) ? w0 : (jid == 1) ? a0 : v0;
  const int K = (jid == 3) ? 256 : 128;
  const int tid = threadIdx.x;
  const int wave = tid >> 6, lane = tid & 63;
  const int lrow = lane & 15, lkg = lane >> 4;
  const int wm = wave >> 1, wn = wave & 1;
  const int bm = lb >> 4, bn = lb & 15;
  const u16* Abase = A + (long)bm * 128 * K;
  const u16* Bbase = B + (long)bn * 128 * K;

  GEMM128_BODY(Abase, Bbase, K)

  const int row0 = bm * 128 + wm * 64 + lkg * 4;
  const int col0 = bn * 128 + wn * 64 + lrow;
#pragma unroll
  for (int mi = 0; mi < 4; ++mi)
#pragma unroll
    for (int ni = 0; ni < 4; ++ni) {
      const int col = col0 + ni * 16;
#pragma unroll
      for (int r = 0; r < 4; ++r) {
        const long o = (long)(row0 + mi * 16 + r) * 2048 + col;
        const float v = acc[mi][ni][r];
        if (jid == 0) {
          const float zz = -(v + bias[col]);
          const float sp = fmaxf(zz, 0.f) + log1pf(expf(-fabsf(zz)));
          wsec[o] = -sp - 0.5f;
        } else if (jid == 1) {
          asec[o] = 1.f / (1.f + expf(-(v + bias[col])));
        } else if (jid == 2) {
          vs[o] = f2b(1.f / (1.f + expf(-(v + bias[col]))));
        } else {
          gb[o] = f2b(v);
        }
      }
    }
}

// ---------------- GEMM 256x256, m201-style quadrant phases (64 sections — count fixed) ----------------
// Section P=0..63 covers K-slice 32P..32P+31 via units {2P (A), 2P+1 (B)}.
// Two 16-MFMA phases per section: {pre-barrier reads; stage 1 unit; barrier;
// setprio(1); 16 MFMA; setprio(0); barrier}. One counted vmcnt per section,
// BEFORE the final barrier (vmcnt -> barrier -> reads ordering).
// r17/r18 bug: loop ran 32 sections (half of K). Fixed: 64 sections,
// stage while P<=60 (units through 127), vmcnt(4) P<=60, vmcnt(0) P==61.
template<int OP>  // 0=f32 out, 1=bf16 out
__global__ __launch_bounds__(512, 2) void gemm256(
    const u16* __restrict__ A0, const u16* __restrict__ B0, void* __restrict__ C0,
    const u16* __restrict__ A1, const u16* __restrict__ B1, void* __restrict__ C1,
    const u16* __restrict__ A2, const u16* __restrict__ B2, void* __restrict__ C2)
{
  __shared__ __align__(16) u16 lds[8 * 8192];
  const int tid = threadIdx.x;
  const int wave = tid >> 6, lane = tid & 63;
  const int lrow = lane & 15, lq = lane >> 4;
  const int wm = wave >> 2, wn = wave & 3;
  const int job = blockIdx.x >> 8;
  const int d = blockIdx.x & 255;
  const int lb = ((d & 7) << 5) | (d >> 3);   // bijective XCD swizzle
  const int bm = lb >> 3, bn = lb & 7;

  const u16* Aj = (job == 0) ? A0 : ((job == 1) ? A1 : A2);
  const u16* Bj = (job == 0) ? B0 : ((job == 1) ? B1 : B2);
  void* Cj      = (job == 0) ? C0 : ((job == 1) ? C1 : C2);

  const u16* __restrict__ Ab = Aj + (long)bm * 256 * 2048;
  const u16* __restrict__ Bb = Bj + (long)bn * 256 * 2048;

  int srco[2], dsto[2];
#pragma unroll
  for (int l = 0; l < 2; ++l) {
    const int c = l * 512 + tid;
    const int row = c >> 2, q = c & 3;
    const int qs = q ^ ((row >> 1) & 3);
    srco[l] = row * 2048 + qs * 8;
    dsto[l] = (l * 512 + wave * 64) * 8;
  }
  int offA[2][4], offB[4];
#pragma unroll
  for (int qm = 0; qm < 2; ++qm)
#pragma unroll
    for (int mi = 0; mi < 4; ++mi) {
      const int r = wm * 128 + qm * 64 + mi * 16 + lrow;
      offA[qm][mi] = r * 32 + (lq ^ ((r >> 1) & 3)) * 8;
    }
#pragma unroll
  for (int ni = 0; ni < 4; ++ni) {
    const int r = wn * 64 + ni * 16 + lrow;
    offB[ni] = r * 32 + (lq ^ ((r >> 1) & 3)) * 8;
  }

  floatx4 acc[8][4];
#pragma unroll
  for (int i = 0; i < 8; ++i)
#pragma unroll
    for (int jq = 0; jq < 4; ++jq) acc[i][jq] = (floatx4)0.f;

#define STAGE(sU, slot) {                                                  \
    const int t_ = (sU) >> 2, j_ = (sU) & 3;                               \
    const u16* base_ = (j_ & 1) ? Bb : Ab;                                 \
    const int kofs_ = t_ * 64 + ((j_ & 2) ? 32 : 0);                       \
    gld16(base_ + srco[0] + kofs_, &lds[(slot) * 8192 + dsto[0]]);         \
    gld16(base_ + srco[1] + kofs_, &lds[(slot) * 8192 + dsto[1]]);         \
  }

  // prologue: stage units 0..5; vmcnt(4) -> units 0..3 landed; barrier.
#pragma unroll
  for (int s = 0; s < 6; ++s) STAGE(s, s);
  asm volatile("s_waitcnt vmcnt(4)" ::: "memory");
  asm volatile("s_barrier" ::: "memory");

#define SEC(P, sA_, sB_, sS0, sS1)                                             \
  {                                                                            \
    short8 af0[4], af1[4], bfv[4];                                             \
    /* ---- qm0 phase: read B + A[qm0] pre-barrier ---- */                     \
    _Pragma("unroll")                                                          \
    for (int ni = 0; ni < 4; ++ni)                                             \
      bfv[ni] = *(const short8*)&lds[(sB_) * 8192 + offB[ni]];                 \
    _Pragma("unroll")                                                          \
    for (int mi = 0; mi < 4; ++mi)                                             \
      af0[mi] = *(const short8*)&lds[(sA_) * 8192 + offA[0][mi]];              \
    if ((P) <= 60) { STAGE(2 * (P) + 6, sS0); }                                \
    asm volatile("s_barrier" ::: "memory");                                    \
    __builtin_amdgcn_s_setprio(1);                                             \
    _Pragma("unroll")                                                          \
    for (int mi = 0; mi < 4; ++mi)                                             \
      _Pragma("unroll")                                                        \
      for (int ni = 0; ni < 4; ++ni)                                           \
        acc[mi][ni] = __builtin_amdgcn_mfma_f32_16x16x32_bf16(af0[mi], bfv[ni], acc[mi][ni], 0, 0, 0); \
    __builtin_amdgcn_s_setprio(0);                                             \
    asm volatile("s_barrier" ::: "memory");                                    \
    /* ---- qm1 phase: read A[qm1] pre-barrier ---- */                         \
    _Pragma("unroll")                                                          \
    for (int mi = 0; mi < 4; ++mi)                                             \
      af1[mi] = *(const short8*)&lds[(sA_) * 8192 + offA[1][mi]];              \
    if ((P) <= 60) { STAGE(2 * (P) + 7, sS1); }                                \
    asm volatile("s_barrier" ::: "memory");                                    \
    __builtin_amdgcn_s_setprio(1);                                             \
    _Pragma("unroll")                                                          \
    for (int mi = 0; mi < 4; ++mi)                                             \
      _Pragma("unroll")                                                        \
      for (int ni = 0; ni < 4; ++ni)                                           \
        acc[4 + mi][ni] = __builtin_amdgcn_mfma_f32_16x16x32_bf16(af1[mi], bfv[ni], acc[4 + mi][ni], 0, 0, 0); \
    __builtin_amdgcn_s_setprio(0);                                             \
    /* counted vmcnt BEFORE the final barrier */                               \
    if ((P) <= 60)      { asm volatile("s_waitcnt vmcnt(4)" ::: "memory"); }   \
    else if ((P) == 61) { asm volatile("s_waitcnt vmcnt(0)" ::: "memory"); }   \
    asm volatile("s_barrier" ::: "memory");                                    \
  }

  for (int pp = 0; pp < 64; pp += 4) {
    SEC(pp,     0, 1, 6, 7);
    SEC(pp + 1, 2, 3, 0, 1);
    SEC(pp + 2, 4, 5, 2, 3);
    SEC(pp + 3, 6, 7, 4, 5);
  }
#undef SEC
#undef STAGE

  const long row0 = (long)bm * 256 + wm * 128 + lq * 4;
  const int col0 = bn * 256 + wn * 64 + lrow;
#pragma unroll
  for (int mi = 0; mi < 8; ++mi) {
#pragma unroll
    for (int ni = 0; ni < 4; ++ni) {
      const int col = col0 + ni * 16;
#pragma unroll
      for (int r = 0; r < 4; ++r) {
        const long o = (row0 + mi * 16 + r) * 2048 + col;
        const float v = acc[mi][ni][r];
        if constexpr (OP == 0) ((float*)Cj)[o] = v;
        else ((u16*)Cj)[o] = f2b(v);
      }
    }
  }
}

// ---------------- K6: per-head fused epilogue (16 lanes/head, 4 ch/lane) ----------------
DEV float wsum16(float v) {
  v += __shfl_xor(v, 1);  v += __shfl_xor(v, 2);
  v += __shfl_xor(v, 4);  v += __shfl_xor(v, 8);
  return v;
}

__global__ __launch_bounds__(256) void ew_head(
    const u16* __restrict__ r16, const u16* __restrict__ k16,
    float* __restrict__ kkout,
    const float* __restrict__ abuf,
    const u16* __restrict__ v0buf, const u16* __restrict__ vsbuf,
    const u16* __restrict__ gbuf,
    const float* __restrict__ y, const float* __restrict__ vfirst,
    const float* __restrict__ kkc, const float* __restrict__ kac,
    const float* __restrict__ rk, const float* __restrict__ lng,
    const float* __restrict__ lnb, u16* __restrict__ z)
{
  const int tid = threadIdx.x;
  const long gh = (long)blockIdx.x * 16 + (tid >> 4);
  const long m = gh >> 5;
  const int h = (int)(gh & 31);
  const int li = tid & 15;
  const int c = h * 64 + li * 4;
  const long off = (m << 11) + c;

  const ushort4v k0p = *(const ushort4v*)(k16 + off);
  const floatx4 av   = *(const floatx4*)(abuf + off);
  const floatx4 kkcv = *(const floatx4*)(kkc + c);
  const floatx4 kacv = *(const floatx4*)(kac + c);
  float k0[4], kf[4], kr[4];
  float ss = 0.f;
#pragma unroll
  for (int i = 0; i < 4; ++i) {
    k0[i] = b2f(k0p[i]);
    kf[i] = k0[i] * (1.f + (av[i] - 1.f) * kacv[i]);
    kr[i] = k0[i] * kkcv[i];
    ss += kr[i] * kr[i];
  }
  const float nrm = sqrtf(wsum16(ss));
  const float rn = 1.f / fmaxf(nrm, 1e-12f);
  floatx4 kkv;
#pragma unroll
  for (int i = 0; i < 4; ++i) kkv[i] = kr[i] * rn;
  *(floatx4*)(kkout + off) = kkv;

  const floatx4 yv = *(const floatx4*)(y + off);
  const float mu = wsum16(yv[0] + yv[1] + yv[2] + yv[3]) * 0.015625f;
  float dy[4], sv2 = 0.f;
#pragma unroll
  for (int i = 0; i < 4; ++i) { dy[i] = yv[i] - mu; sv2 += dy[i] * dy[i]; }
  const float var = wsum16(sv2) * 0.015625f;
  const float rs = rsqrtf(var + 0.00064f);
  const floatx4 lngv = *(const floatx4*)(lng + c);
  const floatx4 lnbv = *(const floatx4*)(lnb + c);
  float yn[4];
#pragma unroll
  for (int i = 0; i < 4; ++i) yn[i] = dy[i] * rs * lngv[i] + lnbv[i];

  const ushort4v rp = *(const ushort4v*)(r16 + off);
  const floatx4 rkv = *(const floatx4*)(rk + c);
  float dd = 0.f;
#pragma unroll
  for (int i = 0; i < 4; ++i) dd += b2f(rp[i]) * kf[i] * rkv[i];
  const float dot = wsum16(dd);

  const ushort4v v0p = *(const ushort4v*)(v0buf + off);
  const ushort4v vsp = *(const ushort4v*)(vsbuf + off);
  const floatx4 vfv  = *(const floatx4*)(vfirst + off);
  const ushort4v gp  = *(const ushort4v*)(gbuf + off);
  ushort4v zo;
#pragma unroll
  for (int i = 0; i < 4; ++i) {
    const float v0v = b2f(v0p[i]);
    const float vv = v0v + (vfv[i] - v0v) * b2f(vsp[i]);
    zo[i] = f2b((yn[i] + dot * vv) * b2f(gp[i]));
  }
  *(ushort4v*)(z + off) = zo;
}

// ---------------- launch ----------------
extern "C" void kernel_launch(void* const* d_in, const int* in_sizes, int n_in,
                              void* d_out, int out_size, void* d_ws, size_t ws_size,
                              hipStream_t stream)
{
  (void)in_sizes; (void)out_size;
  if (n_in < 29) return;
  const int Mrows = 8192;
  const long C = 2048;
  const long MB_ = (long)Mrows * C;

  const float* x   = (const float*)d_in[0];
  const float* vf  = (const float*)d_in[1];
  const float* y   = (const float*)d_in[2];
  const float* x_r = (const float*)d_in[3];
  const float* x_w = (const float*)d_in[4];
  const float* x_k = (const float*)d_in[5];
  const float* x_v = (const float*)d_in[6];
  const float* x_a = (const float*)d_in[7];
  const float* x_g = (const float*)d_in[8];
  const float* w0  = (const float*)d_in[9];
  const float* w1  = (const float*)d_in[10];
  const float* w2  = (const float*)d_in[11];
  const float* a0  = (const float*)d_in[12];
  const float* a1  = (const float*)d_in[13];
  const float* a2  = (const float*)d_in[14];
  const float* v0  = (const float*)d_in[15];
  const float* v1  = (const float*)d_in[16];
  const float* v2  = (const float*)d_in[17];
  const float* g1  = (const float*)d_in[18];
  const float* g2  = (const float*)d_in[19];
  const float* k_k = (const float*)d_in[20];
  const float* k_a = (const float*)d_in[21];
  const float* r_k = (const float*)d_in[22];
  const float* W_r = (const float*)d_in[23];
  const float* W_k = (const float*)d_in[24];
  const float* W_v = (const float*)d_in[25];
  const float* W_o = (const float*)d_in[26];
  const float* lng = (const float*)d_in[27];
  const float* lnb = (const float*)d_in[28];

  float* out_sec = (float*)d_out;
  float* w_sec   = out_sec + MB_;
  float* a_sec   = w_sec + MB_;
  float* kk_sec  = a_sec + MB_;

  u16* k16 = (u16*)out_sec;
  u16* r16 = (u16*)out_sec + MB_;
  u16* Wr16 = (u16*)w_sec;
  u16* Wk16 = Wr16 + C * C;
  u16* Wv16 = Wk16 + C * C;

  u16* p = (u16*)d_ws;
  u16* xr = p;            p += MB_;
  u16* xk = p;            p += MB_;
  u16* xv = p;            p += MB_;
  u16* xw = p;            p += MB_;
  u16* xa = p;            p += MB_;
  u16* xg = p;            p += MB_;
  u16* Wo16 = p;          p += C * C;
  u16* w1T = p;           p += 128 * C;
  u16* a1T = p;           p += 128 * C;
  u16* v1T = p;           p += 128 * C;
  u16* g1T = p;           p += 256 * C;
  u16* w2T = p;           p += C * 128;
  u16* a2T = p;           p += C * 128;
  u16* v2T = p;           p += C * 128;
  u16* g2T = p;           p += C * 256;
  u16* hw  = p;           p += (long)Mrows * 128;
  u16* ha  = p;           p += (long)Mrows * 128;
  u16* hv  = p;           p += (long)Mrows * 128;
  u16* hg  = p;           p += (long)Mrows * 256;
  const size_t need = (size_t)((char*)p - (char*)d_ws);
  if (ws_size < need) return;

  u16* v0buf = xg;
  u16* zbuf  = xk;
  u16* vsbuf = xw;
  u16* gbuf  = xa;

  prep<<<32768, 256, 0, stream>>>(x, x_r, x_k, x_v, x_w, x_a, x_g,
                                  xr, xk, xv, xw, xa, xg,
                                  w1, a1, v1, g1, w2, a2, v2, g2,
                                  w1T, a1T, v1T, g1T, w2T, a2T, v2T, g2T,
                                  W_r, W_k, W_v, W_o, Wr16, Wk16, Wv16, Wo16);
  gemm_s1<<<320, 256, 0, stream>>>(xw, w1T, hw, xa, a1T, ha,
                                   xv, v1T, hv, xg, g1T, hg);
  gemm256<1><<<768, 512, 0, stream>>>(xr, Wr16, r16,
                                      xk, Wk16, k16,
                                      xv, Wv16, v0buf);
  gemm_s2<<<4096, 256, 0, stream>>>(hw, w2T, w_sec, w0,
                                    ha, a2T, a_sec, a0,
                                    hv, v2T, vsbuf, v0,
                                    hg, g2T, gbuf);
  ew_head<<<16384, 256, 0, stream>>>(r16, k16, kk_sec, a_sec, v0buf, vsbuf, gbuf,
                                     y, vf, k_k, k_a, r_k, lng, lnb, zbuf);
  gemm256<0><<<256, 512, 0, stream>>>(zbuf, Wo16, out_sec,
                                      zbuf, Wo16, out_sec,
                                      zbuf, Wo16, out_sec);
}

// Round 20
// 667.166 us; speedup vs baseline: 1.0142x; 1.0142x over previous
//
#include <hip/hip_runtime.h>
#include <math.h>

typedef unsigned short u16;
typedef __attribute__((ext_vector_type(8))) short short8;
typedef __attribute__((ext_vector_type(4))) float floatx4;
typedef __attribute__((ext_vector_type(4))) unsigned short ushort4v;
typedef __attribute__((ext_vector_type(8))) unsigned short ushort8v;

#define DEV static __device__ __forceinline__

DEV u16 f2b(float f) {
  unsigned u = __builtin_bit_cast(unsigned, f);
  u += 0x7fffu + ((u >> 16) & 1u);
  return (u16)(u >> 16);
}
DEV float b2f(u16 h) { return __builtin_bit_cast(float, ((unsigned)h) << 16); }

DEV void gld16(const u16* g, u16* l) {
  __builtin_amdgcn_global_load_lds((__attribute__((address_space(1))) void*)(g),
                                   (__attribute__((address_space(3))) void*)(l), 16, 0, 0);
}

// ---------------- K1: merged prep: token-shift mixes + LoRA transposes + weight casts ----------------
__global__ __launch_bounds__(256) void prep(
    const float* __restrict__ x,
    const float* __restrict__ cr, const float* __restrict__ ck,
    const float* __restrict__ cv, const float* __restrict__ cw,
    const float* __restrict__ ca, const float* __restrict__ cg,
    u16* __restrict__ oxr, u16* __restrict__ oxk, u16* __restrict__ oxv,
    u16* __restrict__ oxw, u16* __restrict__ oxa, u16* __restrict__ oxg,
    const float* __restrict__ w1, const float* __restrict__ a1,
    const float* __restrict__ v1, const float* __restrict__ g1,
    const float* __restrict__ w2, const float* __restrict__ a2,
    const float* __restrict__ v2, const float* __restrict__ g2,
    u16* __restrict__ w1T, u16* __restrict__ a1T, u16* __restrict__ v1T,
    u16* __restrict__ g1T, u16* __restrict__ w2T, u16* __restrict__ a2T,
    u16* __restrict__ v2T, u16* __restrict__ g2T,
    const float* __restrict__ Wr, const float* __restrict__ Wk,
    const float* __restrict__ Wv, const float* __restrict__ Wo,
    u16* __restrict__ Wr16, u16* __restrict__ Wk16,
    u16* __restrict__ Wv16, u16* __restrict__ Wo16)
{
  const int bid = blockIdx.x;
  if (bid < 8192) {
    const long idx = (long)bid * 256 + threadIdx.x;
    const long row = idx >> 8;
    const int c8 = (int)(idx & 255) << 3;
    const long off = (row << 11) + c8;
    const floatx4 xa_ = *(const floatx4*)(x + off);
    const floatx4 xb_ = *(const floatx4*)(x + off + 4);
    floatx4 pa = (floatx4)0.f, pb = (floatx4)0.f;
    if ((row & 4095) != 0) {
      pa = *(const floatx4*)(x + off - 2048);
      pb = *(const floatx4*)(x + off - 2044);
    }
    floatx4 da, db;
#pragma unroll
    for (int i = 0; i < 4; ++i) { da[i] = pa[i] - xa_[i]; db[i] = pb[i] - xb_[i]; }
#define EMIT(cp, op) {                                                         \
    const floatx4 c0 = *(const floatx4*)(cp + c8);                             \
    const floatx4 c1 = *(const floatx4*)(cp + c8 + 4);                         \
    ushort8v o;                                                                \
    _Pragma("unroll")                                                          \
    for (int i = 0; i < 4; ++i) {                                              \
      o[i]     = f2b(xa_[i] + da[i] * c0[i]);                                  \
      o[4 + i] = f2b(xb_[i] + db[i] * c1[i]);                                  \
    }                                                                          \
    *(ushort8v*)(op + off) = o; }
    EMIT(cr, oxr); EMIT(ck, oxk); EMIT(cv, oxv);
    EMIT(cw, oxw); EMIT(ca, oxa); EMIT(cg, oxg);
#undef EMIT
    return;
  }
  const int tb = bid - 8192;
  const int by = tb >> 11;
  const long idx = (long)(tb & 2047) * 256 + threadIdx.x;
  if (by >= 8) {
    const float* s; u16* d;
    switch (by) {
      case 8:  s = Wr; d = Wr16; break;
      case 9:  s = Wk; d = Wk16; break;
      case 10: s = Wv; d = Wv16; break;
      default: s = Wo; d = Wo16; break;
    }
    const long i = idx * 8;
    const float4 a = *(const float4*)(s + i);
    const float4 b = *(const float4*)(s + i + 4);
    ushort4v lo = { f2b(a.x), f2b(a.y), f2b(a.z), f2b(a.w) };
    ushort4v hi = { f2b(b.x), f2b(b.y), f2b(b.z), f2b(b.w) };
    *(ushort4v*)(d + i) = lo;
    *(ushort4v*)(d + i + 4) = hi;
    return;
  }
  const float* src; u16* dst; int sk, sn, dn, dk;
  switch (by) {
    case 0: src = w1; dst = w1T; sk = 2048; sn = 128; dn = 128;  dk = 2048; break;
    case 1: src = a1; dst = a1T; sk = 2048; sn = 128; dn = 128;  dk = 2048; break;
    case 2: src = v1; dst = v1T; sk = 2048; sn = 64;  dn = 128;  dk = 2048; break;
    case 3: src = g1; dst = g1T; sk = 2048; sn = 224; dn = 256;  dk = 2048; break;
    case 4: src = w2; dst = w2T; sk = 128;  sn = 2048; dn = 2048; dk = 128; break;
    case 5: src = a2; dst = a2T; sk = 128;  sn = 2048; dn = 2048; dk = 128; break;
    case 6: src = v2; dst = v2T; sk = 64;   sn = 2048; dn = 2048; dk = 128; break;
    default:src = g2; dst = g2T; sk = 224;  sn = 2048; dn = 2048; dk = 256; break;
  }
  const long total = (long)dn * dk;
  if (idx >= total) return;
  const int n = (int)(idx / dk), k = (int)(idx % dk);
  float v = 0.f;
  if (k < sk && n < sn) v = src[(long)k * sn + n];
  dst[idx] = f2b(v);
}

// ---------------- shared 128x128 GEMM body (m97 structure) ----------------
#define GEMM128_BODY(Abase, Bbase, K)                                          \
  floatx4 acc[4][4];                                                           \
  _Pragma("unroll")                                                            \
  for (int i = 0; i < 4; ++i)                                                  \
    _Pragma("unroll")                                                          \
    for (int jq = 0; jq < 4; ++jq) acc[i][jq] = (floatx4)0.f;                  \
  const int nK = (K) >> 6;                                                     \
  for (int kt = 0; kt < nK; ++kt) {                                            \
    const int k0 = kt << 6;                                                    \
    __syncthreads();                                                           \
    _Pragma("unroll")                                                          \
    for (int i = 0; i < 4; ++i) {                                              \
      const int c = i * 256 + tid;                                             \
      const int row = c >> 3;                                                  \
      const int sch = (c & 7) ^ (row & 7);                                     \
      const long goff = (long)row * (K) + k0 + sch * 8;                        \
      const int lbase = (i * 256 + wave * 64) * 8;                             \
      gld16((Abase) + goff, &sA[lbase]);                                       \
      gld16((Bbase) + goff, &sB[lbase]);                                       \
    }                                                                          \
    asm volatile("s_waitcnt vmcnt(0)" ::: "memory");                           \
    __syncthreads();                                                           \
    _Pragma("unroll")                                                          \
    for (int ks = 0; ks < 2; ++ks) {                                           \
      short8 af[4], bfr[4];                                                    \
      _Pragma("unroll")                                                        \
      for (int mi = 0; mi < 4; ++mi) {                                         \
        const int row = wm * 64 + mi * 16 + lrow;                              \
        const int ch = (ks * 4 + lkg) ^ (row & 7);                             \
        af[mi] = *(const short8*)&sA[row * 64 + ch * 8];                       \
      }                                                                        \
      _Pragma("unroll")                                                        \
      for (int ni = 0; ni < 4; ++ni) {                                         \
        const int row = wn * 64 + ni * 16 + lrow;                              \
        const int ch = (ks * 4 + lkg) ^ (row & 7);                             \
        bfr[ni] = *(const short8*)&sB[row * 64 + ch * 8];                      \
      }                                                                        \
      _Pragma("unroll")                                                        \
      for (int mi = 0; mi < 4; ++mi)                                           \
        _Pragma("unroll")                                                      \
        for (int ni = 0; ni < 4; ++ni)                                         \
          acc[mi][ni] = __builtin_amdgcn_mfma_f32_16x16x32_bf16(af[mi], bfr[ni], acc[mi][ni], 0, 0, 0); \
    }                                                                          \
  }

// ---------------- merged LoRA stage-1: 4 jobs, one launch ----------------
__global__ __launch_bounds__(256, 2) void gemm_s1(
    const u16* __restrict__ xw, const u16* __restrict__ w1T, u16* __restrict__ hw,
    const u16* __restrict__ xa, const u16* __restrict__ a1T, u16* __restrict__ ha,
    const u16* __restrict__ xv, const u16* __restrict__ v1T, u16* __restrict__ hv,
    const u16* __restrict__ xg, const u16* __restrict__ g1T, u16* __restrict__ hg)
{
  __shared__ __align__(16) u16 sA[128 * 64];
  __shared__ __align__(16) u16 sB[128 * 64];
  const int bid = blockIdx.x;
  const int jid = (bid < 64) ? 0 : (bid < 128) ? 1 : (bid < 192) ? 2 : 3;
  const u16* A = (jid == 0) ? xw : (jid == 1) ? xa : (jid == 2) ? xv : xg;
  const u16* B = (jid == 0) ? w1T : (jid == 1) ? a1T : (jid == 2) ? v1T : g1T;
  u16* Cv = (jid == 0) ? hw : (jid == 1) ? ha : (jid == 2) ? hv : hg;
  const int N = (jid == 3) ? 256 : 128;
  const int lb = bid - ((jid == 0) ? 0 : (jid == 1) ? 64 : (jid == 2) ? 128 : 192);
  const int tid = threadIdx.x;
  const int wave = tid >> 6, lane = tid & 63;
  const int lrow = lane & 15, lkg = lane >> 4;
  const int wm = wave >> 1, wn = wave & 1;
  const int nbn = N >> 7;
  const int bm = lb / nbn, bn = lb % nbn;
  const u16* Abase = A + (long)bm * 128 * 2048;
  const u16* Bbase = B + (long)bn * 128 * 2048;

  GEMM128_BODY(Abase, Bbase, 2048)

  const int row0 = bm * 128 + wm * 64 + lkg * 4;
  const int col0 = bn * 128 + wn * 64 + lrow;
#pragma unroll
  for (int mi = 0; mi < 4; ++mi)
#pragma unroll
    for (int ni = 0; ni < 4; ++ni) {
      const int col = col0 + ni * 16;
#pragma unroll
      for (int r = 0; r < 4; ++r) {
        const long o = (long)(row0 + mi * 16 + r) * N + col;
        float v = acc[mi][ni][r];
        if (jid == 0) v = tanhf(v);
        else if (jid == 3) v = 1.f / (1.f + expf(-v));
        Cv[o] = f2b(v);
      }
    }
}

// ---------------- merged LoRA stage-2: 4 jobs x 1024 blocks ----------------
__global__ __launch_bounds__(256, 2) void gemm_s2(
    const u16* __restrict__ hw, const u16* __restrict__ w2T, float* __restrict__ wsec, const float* __restrict__ w0,
    const u16* __restrict__ ha, const u16* __restrict__ a2T, float* __restrict__ asec, const float* __restrict__ a0,
    const u16* __restrict__ hv, const u16* __restrict__ v2T, u16* __restrict__ vs, const float* __restrict__ v0,
    const u16* __restrict__ hg, const u16* __restrict__ g2T, u16* __restrict__ gb)
{
  __shared__ __align__(16) u16 sA[128 * 64];
  __shared__ __align__(16) u16 sB[128 * 64];
  const int jid = blockIdx.x >> 10;
  const int lb = blockIdx.x & 1023;
  const u16* A = (jid == 0) ? hw : (jid == 1) ? ha : (jid == 2) ? hv : hg;
  const u16* B = (jid == 0) ? w2T : (jid == 1) ? a2T : (jid == 2) ? v2T : g2T;
  const float* bias = (jid == 0) ? w0 : (jid == 1) ? a0 : v0;
  const int K = (jid == 3) ? 256 : 128;
  const int tid = threadIdx.x;
  const int wave = tid >> 6, lane = tid & 63;
  const int lrow = lane & 15, lkg = lane >> 4;
  const int wm = wave >> 1, wn = wave & 1;
  const int bm = lb >> 4, bn = lb & 15;
  const u16* Abase = A + (long)bm * 128 * K;
  const u16* Bbase = B + (long)bn * 128 * K;

  GEMM128_BODY(Abase, Bbase, K)

  const int row0 = bm * 128 + wm * 64 + lkg * 4;
  const int col0 = bn * 128 + wn * 64 + lrow;
#pragma unroll
  for (int mi = 0; mi < 4; ++mi)
#pragma unroll
    for (int ni = 0; ni < 4; ++ni) {
      const int col = col0 + ni * 16;
#pragma unroll
      for (int r = 0; r < 4; ++r) {
        const long o = (long)(row0 + mi * 16 + r) * 2048 + col;
        const float v = acc[mi][ni][r];
        if (jid == 0) {
          const float zz = -(v + bias[col]);
          const float sp = fmaxf(zz, 0.f) + log1pf(expf(-fabsf(zz)));
          wsec[o] = -sp - 0.5f;
        } else if (jid == 1) {
          asec[o] = 1.f / (1.f + expf(-(v + bias[col])));
        } else if (jid == 2) {
          vs[o] = f2b(1.f / (1.f + expf(-(v + bias[col]))));
        } else {
          gb[o] = f2b(v);
        }
      }
    }
}

// ---------------- GEMM 256x256, read-early sections (best measured: 195us, 46-48% MfmaUtil) ----------------
template<int OP>  // 0=f32 out, 1=bf16 out
__global__ __launch_bounds__(512, 2) void gemm256(
    const u16* __restrict__ A0, const u16* __restrict__ B0, void* __restrict__ C0,
    const u16* __restrict__ A1, const u16* __restrict__ B1, void* __restrict__ C1,
    const u16* __restrict__ A2, const u16* __restrict__ B2, void* __restrict__ C2)
{
  __shared__ __align__(16) u16 lds[8 * 8192];
  const int tid = threadIdx.x;
  const int wave = tid >> 6, lane = tid & 63;
  const int lrow = lane & 15, lq = lane >> 4;
  const int wm = wave >> 2, wn = wave & 3;
  const int job = blockIdx.x >> 8;
  const int d = blockIdx.x & 255;
  const int lb = ((d & 7) << 5) | (d >> 3);   // bijective XCD swizzle
  const int bm = lb >> 3, bn = lb & 7;

  const u16* Aj = (job == 0) ? A0 : ((job == 1) ? A1 : A2);
  const u16* Bj = (job == 0) ? B0 : ((job == 1) ? B1 : B2);
  void* Cj      = (job == 0) ? C0 : ((job == 1) ? C1 : C2);

  const u16* __restrict__ Ab = Aj + (long)bm * 256 * 2048;
  const u16* __restrict__ Bb = Bj + (long)bn * 256 * 2048;

  int srco[2], dsto[2];
#pragma unroll
  for (int l = 0; l < 2; ++l) {
    const int c = l * 512 + tid;
    const int row = c >> 2, q = c & 3;
    const int qs = q ^ ((row >> 1) & 3);
    srco[l] = row * 2048 + qs * 8;
    dsto[l] = (l * 512 + wave * 64) * 8;
  }
  int offA[2][4], offB[4];
#pragma unroll
  for (int qm = 0; qm < 2; ++qm)
#pragma unroll
    for (int mi = 0; mi < 4; ++mi) {
      const int r = wm * 128 + qm * 64 + mi * 16 + lrow;
      offA[qm][mi] = r * 32 + (lq ^ ((r >> 1) & 3)) * 8;
    }
#pragma unroll
  for (int ni = 0; ni < 4; ++ni) {
    const int r = wn * 64 + ni * 16 + lrow;
    offB[ni] = r * 32 + (lq ^ ((r >> 1) & 3)) * 8;
  }

  floatx4 acc[8][4];
#pragma unroll
  for (int i = 0; i < 8; ++i)
#pragma unroll
    for (int jq = 0; jq < 4; ++jq) acc[i][jq] = (floatx4)0.f;

#define STAGE(sU, slot) {                                                  \
    const int t_ = (sU) >> 2, j_ = (sU) & 3;                               \
    const u16* base_ = (j_ & 1) ? Bb : Ab;                                 \
    const int kofs_ = t_ * 64 + ((j_ & 2) ? 32 : 0);                       \
    gld16(base_ + srco[0] + kofs_, &lds[(slot) * 8192 + dsto[0]]);         \
    gld16(base_ + srco[1] + kofs_, &lds[(slot) * 8192 + dsto[1]]);         \
  }

#pragma unroll
  for (int s = 0; s < 6; ++s) STAGE(s, s);
  asm volatile("s_waitcnt vmcnt(4)" ::: "memory");
  asm volatile("s_barrier" ::: "memory");

#define SEC(P, sA_, sB_, sS0, sS1)                                             \
  {                                                                            \
    short8 af0[4], af1[4], bfv[4];                                             \
    _Pragma("unroll")                                                          \
    for (int mi = 0; mi < 4; ++mi)                                             \
      af0[mi] = *(const short8*)&lds[(sA_) * 8192 + offA[0][mi]];              \
    _Pragma("unroll")                                                          \
    for (int ni = 0; ni < 4; ++ni)                                             \
      bfv[ni] = *(const short8*)&lds[(sB_) * 8192 + offB[ni]];                 \
    _Pragma("unroll")                                                          \
    for (int mi = 0; mi < 4; ++mi)                                             \
      af1[mi] = *(const short8*)&lds[(sA_) * 8192 + offA[1][mi]];              \
    if ((P) < 61) { asm volatile("s_waitcnt vmcnt(4)" ::: "memory"); }         \
    else          { asm volatile("s_waitcnt vmcnt(0)" ::: "memory"); }         \
    asm volatile("s_barrier" ::: "memory");                                    \
    if ((P) <= 60) {                                                           \
      STAGE(2 * (P) + 6, sS0);                                                 \
      STAGE(2 * (P) + 7, sS1);                                                 \
    }                                                                          \
    _Pragma("unroll")                                                          \
    for (int mi = 0; mi < 4; ++mi)                                             \
      _Pragma("unroll")                                                        \
      for (int ni = 0; ni < 4; ++ni)                                           \
        acc[mi][ni] = __builtin_amdgcn_mfma_f32_16x16x32_bf16(af0[mi], bfv[ni], acc[mi][ni], 0, 0, 0); \
    _Pragma("unroll")                                                          \
    for (int mi = 0; mi < 4; ++mi)                                             \
      _Pragma("unroll")                                                        \
      for (int ni = 0; ni < 4; ++ni)                                           \
        acc[4 + mi][ni] = __builtin_amdgcn_mfma_f32_16x16x32_bf16(af1[mi], bfv[ni], acc[4 + mi][ni], 0, 0, 0); \
  }

  for (int pp = 0; pp < 64; pp += 4) {
    SEC(pp,     0, 1, 6, 7);
    SEC(pp + 1, 2, 3, 0, 1);
    SEC(pp + 2, 4, 5, 2, 3);
    SEC(pp + 3, 6, 7, 4, 5);
  }
#undef SEC
#undef STAGE

  const long row0 = (long)bm * 256 + wm * 128 + lq * 4;
  const int col0 = bn * 256 + wn * 64 + lrow;
#pragma unroll
  for (int mi = 0; mi < 8; ++mi) {
#pragma unroll
    for (int ni = 0; ni < 4; ++ni) {
      const int col = col0 + ni * 16;
#pragma unroll
      for (int r = 0; r < 4; ++r) {
        const long o = (row0 + mi * 16 + r) * 2048 + col;
        const float v = acc[mi][ni][r];
        if constexpr (OP == 0) ((float*)Cj)[o] = v;
        else ((u16*)Cj)[o] = f2b(v);
      }
    }
  }
}

// ---------------- K6: per-head fused epilogue (16 lanes/head, 4 ch/lane) ----------------
DEV float wsum16(float v) {
  v += __shfl_xor(v, 1);  v += __shfl_xor(v, 2);
  v += __shfl_xor(v, 4);  v += __shfl_xor(v, 8);
  return v;
}

__global__ __launch_bounds__(256) void ew_head(
    const u16* __restrict__ r16, const u16* __restrict__ k16,
    float* __restrict__ kkout,
    const float* __restrict__ abuf,
    const u16* __restrict__ v0buf, const u16* __restrict__ vsbuf,
    const u16* __restrict__ gbuf,
    const float* __restrict__ y, const float* __restrict__ vfirst,
    const float* __restrict__ kkc, const float* __restrict__ kac,
    const float* __restrict__ rk, const float* __restrict__ lng,
    const float* __restrict__ lnb, u16* __restrict__ z)
{
  const int tid = threadIdx.x;
  const long gh = (long)blockIdx.x * 16 + (tid >> 4);
  const long m = gh >> 5;
  const int h = (int)(gh & 31);
  const int li = tid & 15;
  const int c = h * 64 + li * 4;
  const long off = (m << 11) + c;

  const ushort4v k0p = *(const ushort4v*)(k16 + off);
  const floatx4 av   = *(const floatx4*)(abuf + off);
  const floatx4 kkcv = *(const floatx4*)(kkc + c);
  const floatx4 kacv = *(const floatx4*)(kac + c);
  float k0[4], kf[4], kr[4];
  float ss = 0.f;
#pragma unroll
  for (int i = 0; i < 4; ++i) {
    k0[i] = b2f(k0p[i]);
    kf[i] = k0[i] * (1.f + (av[i] - 1.f) * kacv[i]);
    kr[i] = k0[i] * kkcv[i];
    ss += kr[i] * kr[i];
  }
  const float nrm = sqrtf(wsum16(ss));
  const float rn = 1.f / fmaxf(nrm, 1e-12f);
  floatx4 kkv;
#pragma unroll
  for (int i = 0; i < 4; ++i) kkv[i] = kr[i] * rn;
  *(floatx4*)(kkout + off) = kkv;

  const floatx4 yv = *(const floatx4*)(y + off);
  const float mu = wsum16(yv[0] + yv[1] + yv[2] + yv[3]) * 0.015625f;
  float dy[4], sv2 = 0.f;
#pragma unroll
  for (int i = 0; i < 4; ++i) { dy[i] = yv[i] - mu; sv2 += dy[i] * dy[i]; }
  const float var = wsum16(sv2) * 0.015625f;
  const float rs = rsqrtf(var + 0.00064f);
  const floatx4 lngv = *(const floatx4*)(lng + c);
  const floatx4 lnbv = *(const floatx4*)(lnb + c);
  float yn[4];
#pragma unroll
  for (int i = 0; i < 4; ++i) yn[i] = dy[i] * rs * lngv[i] + lnbv[i];

  const ushort4v rp = *(const ushort4v*)(r16 + off);
  const floatx4 rkv = *(const floatx4*)(rk + c);
  float dd = 0.f;
#pragma unroll
  for (int i = 0; i < 4; ++i) dd += b2f(rp[i]) * kf[i] * rkv[i];
  const float dot = wsum16(dd);

  const ushort4v v0p = *(const ushort4v*)(v0buf + off);
  const ushort4v vsp = *(const ushort4v*)(vsbuf + off);
  const floatx4 vfv  = *(const floatx4*)(vfirst + off);
  const ushort4v gp  = *(const ushort4v*)(gbuf + off);
  ushort4v zo;
#pragma unroll
  for (int i = 0; i < 4; ++i) {
    const float v0v = b2f(v0p[i]);
    const float vv = v0v + (vfv[i] - v0v) * b2f(vsp[i]);
    zo[i] = f2b((yn[i] + dot * vv) * b2f(gp[i]));
  }
  *(ushort4v*)(z + off) = zo;
}

// ---------------- launch ----------------
extern "C" void kernel_launch(void* const* d_in, const int* in_sizes, int n_in,
                              void* d_out, int out_size, void* d_ws, size_t ws_size,
                              hipStream_t stream)
{
  (void)in_sizes; (void)out_size;
  if (n_in < 29) return;
  const int Mrows = 8192;
  const long C = 2048;
  const long MB_ = (long)Mrows * C;

  const float* x   = (const float*)d_in[0];
  const float* vf  = (const float*)d_in[1];
  const float* y   = (const float*)d_in[2];
  const float* x_r = (const float*)d_in[3];
  const float* x_w = (const float*)d_in[4];
  const float* x_k = (const float*)d_in[5];
  const float* x_v = (const float*)d_in[6];
  const float* x_a = (const float*)d_in[7];
  const float* x_g = (const float*)d_in[8];
  const float* w0  = (const float*)d_in[9];
  const float* w1  = (const float*)d_in[10];
  const float* w2  = (const float*)d_in[11];
  const float* a0  = (const float*)d_in[12];
  const float* a1  = (const float*)d_in[13];
  const float* a2  = (const float*)d_in[14];
  const float* v0  = (const float*)d_in[15];
  const float* v1  = (const float*)d_in[16];
  const float* v2  = (const float*)d_in[17];
  const float* g1  = (const float*)d_in[18];
  const float* g2  = (const float*)d_in[19];
  const float* k_k = (const float*)d_in[20];
  const float* k_a = (const float*)d_in[21];
  const float* r_k = (const float*)d_in[22];
  const float* W_r = (const float*)d_in[23];
  const float* W_k = (const float*)d_in[24];
  const float* W_v = (const float*)d_in[25];
  const float* W_o = (const float*)d_in[26];
  const float* lng = (const float*)d_in[27];
  const float* lnb = (const float*)d_in[28];

  float* out_sec = (float*)d_out;
  float* w_sec   = out_sec + MB_;
  float* a_sec   = w_sec + MB_;
  float* kk_sec  = a_sec + MB_;

  u16* k16 = (u16*)out_sec;
  u16* r16 = (u16*)out_sec + MB_;
  u16* Wr16 = (u16*)w_sec;
  u16* Wk16 = Wr16 + C * C;
  u16* Wv16 = Wk16 + C * C;

  u16* p = (u16*)d_ws;
  u16* xr = p;            p += MB_;
  u16* xk = p;            p += MB_;
  u16* xv = p;            p += MB_;
  u16* xw = p;            p += MB_;
  u16* xa = p;            p += MB_;
  u16* xg = p;            p += MB_;
  u16* Wo16 = p;          p += C * C;
  u16* w1T = p;           p += 128 * C;
  u16* a1T = p;           p += 128 * C;
  u16* v1T = p;           p += 128 * C;
  u16* g1T = p;           p += 256 * C;
  u16* w2T = p;           p += C * 128;
  u16* a2T = p;           p += C * 128;
  u16* v2T = p;           p += C * 128;
  u16* g2T = p;           p += C * 256;
  u16* hw  = p;           p += (long)Mrows * 128;
  u16* ha  = p;           p += (long)Mrows * 128;
  u16* hv  = p;           p += (long)Mrows * 128;
  u16* hg  = p;           p += (long)Mrows * 256;
  const size_t need = (size_t)((char*)p - (char*)d_ws);
  if (ws_size < need) return;

  u16* v0buf = xg;
  u16* zbuf  = xk;
  u16* vsbuf = xw;
  u16* gbuf  = xa;

  prep<<<32768, 256, 0, stream>>>(x, x_r, x_k, x_v, x_w, x_a, x_g,
                                  xr, xk, xv, xw, xa, xg,
                                  w1, a1, v1, g1, w2, a2, v2, g2,
                                  w1T, a1T, v1T, g1T, w2T, a2T, v2T, g2T,
                                  W_r, W_k, W_v, W_o, Wr16, Wk16, Wv16, Wo16);
  gemm_s1<<<320, 256, 0, stream>>>(xw, w1T, hw, xa, a1T, ha,
                                   xv, v1T, hv, xg, g1T, hg);
  gemm256<1><<<768, 512, 0, stream>>>(xr, Wr16, r16,
                                      xk, Wk16, k16,
                                      xv, Wv16, v0buf);
  gemm_s2<<<4096, 256, 0, stream>>>(hw, w2T, w_sec, w0,
                                    ha, a2T, a_sec, a0,
                                    hv, v2T, vsbuf, v0,
                                    hg, g2T, gbuf);
  ew_head<<<16384, 256, 0, stream>>>(r16, k16, kk_sec, a_sec, v0buf, vsbuf, gbuf,
                                     y, vf, k_k, k_a, r_k, lng, lnb, zbuf);
  gemm256<0><<<256, 512, 0, stream>>>(zbuf, Wo16, out_sec,
                                      zbuf, Wo16, out_sec,
                                      zbuf, Wo16, out_sec);
}

// Round 21
// 644.740 us; speedup vs baseline: 1.0495x; 1.0348x over previous
//
#include <hip/hip_runtime.h>
#include <math.h>

typedef unsigned short u16;
typedef __attribute__((ext_vector_type(8))) short short8;
typedef __attribute__((ext_vector_type(4))) float floatx4;
typedef __attribute__((ext_vector_type(4))) unsigned short ushort4v;
typedef __attribute__((ext_vector_type(8))) unsigned short ushort8v;

#define DEV static __device__ __forceinline__

DEV u16 f2b(float f) {
  unsigned u = __builtin_bit_cast(unsigned, f);
  u += 0x7fffu + ((u >> 16) & 1u);
  return (u16)(u >> 16);
}
DEV float b2f(u16 h) { return __builtin_bit_cast(float, ((unsigned)h) << 16); }

DEV void gld16(const u16* g, u16* l) {
  __builtin_amdgcn_global_load_lds((__attribute__((address_space(1))) void*)(g),
                                   (__attribute__((address_space(3))) void*)(l), 16, 0, 0);
}

// fast transcendentals: v_exp_f32 / v_rcp_f32 paths (error ~1e-5 rel, ok vs bf16 quantum)
DEV float fexp(float x) { return __expf(x); }
DEV float fsig(float v) { return __builtin_amdgcn_rcpf(1.f + __expf(-v)); }
DEV float ftanh(float v) {
  // tanh(v) = 1 - 2/(e^{2v}+1); saturates correctly for |v| large
  return 1.f - 2.f * __builtin_amdgcn_rcpf(__expf(2.f * v) + 1.f);
}

// ---------------- K1: merged prep: token-shift mixes + LoRA transposes + weight casts ----------------
__global__ __launch_bounds__(256) void prep(
    const float* __restrict__ x,
    const float* __restrict__ cr, const float* __restrict__ ck,
    const float* __restrict__ cv, const float* __restrict__ cw,
    const float* __restrict__ ca, const float* __restrict__ cg,
    u16* __restrict__ oxr, u16* __restrict__ oxk, u16* __restrict__ oxv,
    u16* __restrict__ oxw, u16* __restrict__ oxa, u16* __restrict__ oxg,
    const float* __restrict__ w1, const float* __restrict__ a1,
    const float* __restrict__ v1, const float* __restrict__ g1,
    const float* __restrict__ w2, const float* __restrict__ a2,
    const float* __restrict__ v2, const float* __restrict__ g2,
    u16* __restrict__ w1T, u16* __restrict__ a1T, u16* __restrict__ v1T,
    u16* __restrict__ g1T, u16* __restrict__ w2T, u16* __restrict__ a2T,
    u16* __restrict__ v2T, u16* __restrict__ g2T,
    const float* __restrict__ Wr, const float* __restrict__ Wk,
    const float* __restrict__ Wv, const float* __restrict__ Wo,
    u16* __restrict__ Wr16, u16* __restrict__ Wk16,
    u16* __restrict__ Wv16, u16* __restrict__ Wo16)
{
  const int bid = blockIdx.x;
  if (bid < 8192) {
    const long idx = (long)bid * 256 + threadIdx.x;
    const long row = idx >> 8;
    const int c8 = (int)(idx & 255) << 3;
    const long off = (row << 11) + c8;
    const floatx4 xa_ = *(const floatx4*)(x + off);
    const floatx4 xb_ = *(const floatx4*)(x + off + 4);
    floatx4 pa = (floatx4)0.f, pb = (floatx4)0.f;
    if ((row & 4095) != 0) {
      pa = *(const floatx4*)(x + off - 2048);
      pb = *(const floatx4*)(x + off - 2044);
    }
    floatx4 da, db;
#pragma unroll
    for (int i = 0; i < 4; ++i) { da[i] = pa[i] - xa_[i]; db[i] = pb[i] - xb_[i]; }
#define EMIT(cp, op) {                                                         \
    const floatx4 c0 = *(const floatx4*)(cp + c8);                             \
    const floatx4 c1 = *(const floatx4*)(cp + c8 + 4);                         \
    ushort8v o;                                                                \
    _Pragma("unroll")                                                          \
    for (int i = 0; i < 4; ++i) {                                              \
      o[i]     = f2b(xa_[i] + da[i] * c0[i]);                                  \
      o[4 + i] = f2b(xb_[i] + db[i] * c1[i]);                                  \
    }                                                                          \
    *(ushort8v*)(op + off) = o; }
    EMIT(cr, oxr); EMIT(ck, oxk); EMIT(cv, oxv);
    EMIT(cw, oxw); EMIT(ca, oxa); EMIT(cg, oxg);
#undef EMIT
    return;
  }
  const int tb = bid - 8192;
  const int by = tb >> 11;
  const long idx = (long)(tb & 2047) * 256 + threadIdx.x;
  if (by >= 8) {
    const float* s; u16* d;
    switch (by) {
      case 8:  s = Wr; d = Wr16; break;
      case 9:  s = Wk; d = Wk16; break;
      case 10: s = Wv; d = Wv16; break;
      default: s = Wo; d = Wo16; break;
    }
    const long i = idx * 8;
    const float4 a = *(const float4*)(s + i);
    const float4 b = *(const float4*)(s + i + 4);
    ushort4v lo = { f2b(a.x), f2b(a.y), f2b(a.z), f2b(a.w) };
    ushort4v hi = { f2b(b.x), f2b(b.y), f2b(b.z), f2b(b.w) };
    *(ushort4v*)(d + i) = lo;
    *(ushort4v*)(d + i + 4) = hi;
    return;
  }
  const float* src; u16* dst; int sk, sn, dn, dk;
  switch (by) {
    case 0: src = w1; dst = w1T; sk = 2048; sn = 128; dn = 128;  dk = 2048; break;
    case 1: src = a1; dst = a1T; sk = 2048; sn = 128; dn = 128;  dk = 2048; break;
    case 2: src = v1; dst = v1T; sk = 2048; sn = 64;  dn = 128;  dk = 2048; break;
    case 3: src = g1; dst = g1T; sk = 2048; sn = 224; dn = 256;  dk = 2048; break;
    case 4: src = w2; dst = w2T; sk = 128;  sn = 2048; dn = 2048; dk = 128; break;
    case 5: src = a2; dst = a2T; sk = 128;  sn = 2048; dn = 2048; dk = 128; break;
    case 6: src = v2; dst = v2T; sk = 64;   sn = 2048; dn = 2048; dk = 128; break;
    default:src = g2; dst = g2T; sk = 224;  sn = 2048; dn = 2048; dk = 256; break;
  }
  const long total = (long)dn * dk;
  if (idx >= total) return;
  const int n = (int)(idx / dk), k = (int)(idx % dk);
  float v = 0.f;
  if (k < sk && n < sn) v = src[(long)k * sn + n];
  dst[idx] = f2b(v);
}

// ---------------- shared 128x128 GEMM body (m97 structure) ----------------
#define GEMM128_BODY(Abase, Bbase, K)                                          \
  floatx4 acc[4][4];                                                           \
  _Pragma("unroll")                                                            \
  for (int i = 0; i < 4; ++i)                                                  \
    _Pragma("unroll")                                                          \
    for (int jq = 0; jq < 4; ++jq) acc[i][jq] = (floatx4)0.f;                  \
  const int nK = (K) >> 6;                                                     \
  for (int kt = 0; kt < nK; ++kt) {                                            \
    const int k0 = kt << 6;                                                    \
    __syncthreads();                                                           \
    _Pragma("unroll")                                                          \
    for (int i = 0; i < 4; ++i) {                                              \
      const int c = i * 256 + tid;                                             \
      const int row = c >> 3;                                                  \
      const int sch = (c & 7) ^ (row & 7);                                     \
      const long goff = (long)row * (K) + k0 + sch * 8;                        \
      const int lbase = (i * 256 + wave * 64) * 8;                             \
      gld16((Abase) + goff, &sA[lbase]);                                       \
      gld16((Bbase) + goff, &sB[lbase]);                                       \
    }                                                                          \
    asm volatile("s_waitcnt vmcnt(0)" ::: "memory");                           \
    __syncthreads();                                                           \
    _Pragma("unroll")                                                          \
    for (int ks = 0; ks < 2; ++ks) {                                           \
      short8 af[4], bfr[4];                                                    \
      _Pragma("unroll")                                                        \
      for (int mi = 0; mi < 4; ++mi) {                                         \
        const int row = wm * 64 + mi * 16 + lrow;                              \
        const int ch = (ks * 4 + lkg) ^ (row & 7);                             \
        af[mi] = *(const short8*)&sA[row * 64 + ch * 8];                       \
      }                                                                        \
      _Pragma("unroll")                                                        \
      for (int ni = 0; ni < 4; ++ni) {                                         \
        const int row = wn * 64 + ni * 16 + lrow;                              \
        const int ch = (ks * 4 + lkg) ^ (row & 7);                             \
        bfr[ni] = *(const short8*)&sB[row * 64 + ch * 8];                      \
      }                                                                        \
      _Pragma("unroll")                                                        \
      for (int mi = 0; mi < 4; ++mi)                                           \
        _Pragma("unroll")                                                      \
        for (int ni = 0; ni < 4; ++ni)                                         \
          acc[mi][ni] = __builtin_amdgcn_mfma_f32_16x16x32_bf16(af[mi], bfr[ni], acc[mi][ni], 0, 0, 0); \
    }                                                                          \
  }

// ---------------- merged LoRA stage-1: 4 jobs, one launch ----------------
__global__ __launch_bounds__(256, 2) void gemm_s1(
    const u16* __restrict__ xw, const u16* __restrict__ w1T, u16* __restrict__ hw,
    const u16* __restrict__ xa, const u16* __restrict__ a1T, u16* __restrict__ ha,
    const u16* __restrict__ xv, const u16* __restrict__ v1T, u16* __restrict__ hv,
    const u16* __restrict__ xg, const u16* __restrict__ g1T, u16* __restrict__ hg)
{
  __shared__ __align__(16) u16 sA[128 * 64];
  __shared__ __align__(16) u16 sB[128 * 64];
  const int bid = blockIdx.x;
  const int jid = (bid < 64) ? 0 : (bid < 128) ? 1 : (bid < 192) ? 2 : 3;
  const u16* A = (jid == 0) ? xw : (jid == 1) ? xa : (jid == 2) ? xv : xg;
  const u16* B = (jid == 0) ? w1T : (jid == 1) ? a1T : (jid == 2) ? v1T : g1T;
  u16* Cv = (jid == 0) ? hw : (jid == 1) ? ha : (jid == 2) ? hv : hg;
  const int N = (jid == 3) ? 256 : 128;
  const int lb = bid - ((jid == 0) ? 0 : (jid == 1) ? 64 : (jid == 2) ? 128 : 192);
  const int tid = threadIdx.x;
  const int wave = tid >> 6, lane = tid & 63;
  const int lrow = lane & 15, lkg = lane >> 4;
  const int wm = wave >> 1, wn = wave & 1;
  const int nbn = N >> 7;
  const int bm = lb / nbn, bn = lb % nbn;
  const u16* Abase = A + (long)bm * 128 * 2048;
  const u16* Bbase = B + (long)bn * 128 * 2048;

  GEMM128_BODY(Abase, Bbase, 2048)

  const int row0 = bm * 128 + wm * 64 + lkg * 4;
  const int col0 = bn * 128 + wn * 64 + lrow;
#pragma unroll
  for (int mi = 0; mi < 4; ++mi)
#pragma unroll
    for (int ni = 0; ni < 4; ++ni) {
      const int col = col0 + ni * 16;
#pragma unroll
      for (int r = 0; r < 4; ++r) {
        const long o = (long)(row0 + mi * 16 + r) * N + col;
        float v = acc[mi][ni][r];
        if (jid == 0) v = ftanh(v);
        else if (jid == 3) v = fsig(v);
        Cv[o] = f2b(v);
      }
    }
}

// ---------------- merged LoRA stage-2: 4 jobs x 1024 blocks ----------------
__global__ __launch_bounds__(256, 2) void gemm_s2(
    const u16* __restrict__ hw, const u16* __restrict__ w2T, float* __restrict__ wsec, const float* __restrict__ w0,
    const u16* __restrict__ ha, const u16* __restrict__ a2T, float* __restrict__ asec, const float* __restrict__ a0,
    const u16* __restrict__ hv, const u16* __restrict__ v2T, u16* __restrict__ vs, const float* __restrict__ v0,
    const u16* __restrict__ hg, const u16* __restrict__ g2T, u16* __restrict__ gb)
{
  __shared__ __align__(16) u16 sA[128 * 64];
  __shared__ __align__(16) u16 sB[128 * 64];
  const int jid = blockIdx.x >> 10;
  const int lb = blockIdx.x & 1023;
  const u16* A = (jid == 0) ? hw : (jid == 1) ? ha : (jid == 2) ? hv : hg;
  const u16* B = (jid == 0) ? w2T : (jid == 1) ? a2T : (jid == 2) ? v2T : g2T;
  const float* bias = (jid == 0) ? w0 : (jid == 1) ? a0 : v0;
  const int K = (jid == 3) ? 256 : 128;
  const int tid = threadIdx.x;
  const int wave = tid >> 6, lane = tid & 63;
  const int lrow = lane & 15, lkg = lane >> 4;
  const int wm = wave >> 1, wn = wave & 1;
  const int bm = lb >> 4, bn = lb & 15;
  const u16* Abase = A + (long)bm * 128 * K;
  const u16* Bbase = B + (long)bn * 128 * K;

  GEMM128_BODY(Abase, Bbase, K)

  const int row0 = bm * 128 + wm * 64 + lkg * 4;
  const int col0 = bn * 128 + wn * 64 + lrow;
#pragma unroll
  for (int mi = 0; mi < 4; ++mi)
#pragma unroll
    for (int ni = 0; ni < 4; ++ni) {
      const int col = col0 + ni * 16;
#pragma unroll
      for (int r = 0; r < 4; ++r) {
        const long o = (long)(row0 + mi * 16 + r) * 2048 + col;
        const float v = acc[mi][ni][r];
        if (jid == 0) {
          // w = -softplus(-(v+b)) - 0.5, softplus via fast exp/log1p
          const float zz = -(v + bias[col]);
          const float sp = fmaxf(zz, 0.f) + log1pf(fexp(-fabsf(zz)));
          wsec[o] = -sp - 0.5f;
        } else if (jid == 1) {
          asec[o] = fsig(v + bias[col]);
        } else if (jid == 2) {
          vs[o] = f2b(fsig(v + bias[col]));
        } else {
          gb[o] = f2b(v);
        }
      }
    }
}

// ---------------- GEMM 256x256, read-early sections (best measured: 195us, 46-48% MfmaUtil) ----------------
template<int OP>  // 0=f32 out, 1=bf16 out
__global__ __launch_bounds__(512, 2) void gemm256(
    const u16* __restrict__ A0, const u16* __restrict__ B0, void* __restrict__ C0,
    const u16* __restrict__ A1, const u16* __restrict__ B1, void* __restrict__ C1,
    const u16* __restrict__ A2, const u16* __restrict__ B2, void* __restrict__ C2)
{
  __shared__ __align__(16) u16 lds[8 * 8192];
  const int tid = threadIdx.x;
  const int wave = tid >> 6, lane = tid & 63;
  const int lrow = lane & 15, lq = lane >> 4;
  const int wm = wave >> 2, wn = wave & 3;
  const int job = blockIdx.x >> 8;
  const int d = blockIdx.x & 255;
  const int lb = ((d & 7) << 5) | (d >> 3);   // bijective XCD swizzle
  const int bm = lb >> 3, bn = lb & 7;

  const u16* Aj = (job == 0) ? A0 : ((job == 1) ? A1 : A2);
  const u16* Bj = (job == 0) ? B0 : ((job == 1) ? B1 : B2);
  void* Cj      = (job == 0) ? C0 : ((job == 1) ? C1 : C2);

  const u16* __restrict__ Ab = Aj + (long)bm * 256 * 2048;
  const u16* __restrict__ Bb = Bj + (long)bn * 256 * 2048;

  int srco[2], dsto[2];
#pragma unroll
  for (int l = 0; l < 2; ++l) {
    const int c = l * 512 + tid;
    const int row = c >> 2, q = c & 3;
    const int qs = q ^ ((row >> 1) & 3);
    srco[l] = row * 2048 + qs * 8;
    dsto[l] = (l * 512 + wave * 64) * 8;
  }
  int offA[2][4], offB[4];
#pragma unroll
  for (int qm = 0; qm < 2; ++qm)
#pragma unroll
    for (int mi = 0; mi < 4; ++mi) {
      const int r = wm * 128 + qm * 64 + mi * 16 + lrow;
      offA[qm][mi] = r * 32 + (lq ^ ((r >> 1) & 3)) * 8;
    }
#pragma unroll
  for (int ni = 0; ni < 4; ++ni) {
    const int r = wn * 64 + ni * 16 + lrow;
    offB[ni] = r * 32 + (lq ^ ((r >> 1) & 3)) * 8;
  }

  floatx4 acc[8][4];
#pragma unroll
  for (int i = 0; i < 8; ++i)
#pragma unroll
    for (int jq = 0; jq < 4; ++jq) acc[i][jq] = (floatx4)0.f;

#define STAGE(sU, slot) {                                                  \
    const int t_ = (sU) >> 2, j_ = (sU) & 3;                               \
    const u16* base_ = (j_ & 1) ? Bb : Ab;                                 \
    const int kofs_ = t_ * 64 + ((j_ & 2) ? 32 : 0);                       \
    gld16(base_ + srco[0] + kofs_, &lds[(slot) * 8192 + dsto[0]]);         \
    gld16(base_ + srco[1] + kofs_, &lds[(slot) * 8192 + dsto[1]]);         \
  }

#pragma unroll
  for (int s = 0; s < 6; ++s) STAGE(s, s);
  asm volatile("s_waitcnt vmcnt(4)" ::: "memory");
  asm volatile("s_barrier" ::: "memory");

#define SEC(P, sA_, sB_, sS0, sS1)                                             \
  {                                                                            \
    short8 af0[4], af1[4], bfv[4];                                             \
    _Pragma("unroll")                                                          \
    for (int mi = 0; mi < 4; ++mi)                                             \
      af0[mi] = *(const short8*)&lds[(sA_) * 8192 + offA[0][mi]];              \
    _Pragma("unroll")                                                          \
    for (int ni = 0; ni < 4; ++ni)                                             \
      bfv[ni] = *(const short8*)&lds[(sB_) * 8192 + offB[ni]];                 \
    _Pragma("unroll")                                                          \
    for (int mi = 0; mi < 4; ++mi)                                             \
      af1[mi] = *(const short8*)&lds[(sA_) * 8192 + offA[1][mi]];              \
    if ((P) < 61) { asm volatile("s_waitcnt vmcnt(4)" ::: "memory"); }         \
    else          { asm volatile("s_waitcnt vmcnt(0)" ::: "memory"); }         \
    asm volatile("s_barrier" ::: "memory");                                    \
    if ((P) <= 60) {                                                           \
      STAGE(2 * (P) + 6, sS0);                                                 \
      STAGE(2 * (P) + 7, sS1);                                                 \
    }                                                                          \
    _Pragma("unroll")                                                          \
    for (int mi = 0; mi < 4; ++mi)                                             \
      _Pragma("unroll")                                                        \
      for (int ni = 0; ni < 4; ++ni)                                           \
        acc[mi][ni] = __builtin_amdgcn_mfma_f32_16x16x32_bf16(af0[mi], bfv[ni], acc[mi][ni], 0, 0, 0); \
    _Pragma("unroll")                                                          \
    for (int mi = 0; mi < 4; ++mi)                                             \
      _Pragma("unroll")                                                        \
      for (int ni = 0; ni < 4; ++ni)                                           \
        acc[4 + mi][ni] = __builtin_amdgcn_mfma_f32_16x16x32_bf16(af1[mi], bfv[ni], acc[4 + mi][ni], 0, 0, 0); \
  }

  for (int pp = 0; pp < 64; pp += 4) {
    SEC(pp,     0, 1, 6, 7);
    SEC(pp + 1, 2, 3, 0, 1);
    SEC(pp + 2, 4, 5, 2, 3);
    SEC(pp + 3, 6, 7, 4, 5);
  }
#undef SEC
#undef STAGE

  const long row0 = (long)bm * 256 + wm * 128 + lq * 4;
  const int col0 = bn * 256 + wn * 64 + lrow;
#pragma unroll
  for (int mi = 0; mi < 8; ++mi) {
#pragma unroll
    for (int ni = 0; ni < 4; ++ni) {
      const int col = col0 + ni * 16;
#pragma unroll
      for (int r = 0; r < 4; ++r) {
        const long o = (row0 + mi * 16 + r) * 2048 + col;
        const float v = acc[mi][ni][r];
        if constexpr (OP == 0) ((float*)Cj)[o] = v;
        else ((u16*)Cj)[o] = f2b(v);
      }
    }
  }
}

// ---------------- K6: per-head fused epilogue (16 lanes/head, 4 ch/lane) ----------------
DEV float wsum16(float v) {
  v += __shfl_xor(v, 1);  v += __shfl_xor(v, 2);
  v += __shfl_xor(v, 4);  v += __shfl_xor(v, 8);
  return v;
}

__global__ __launch_bounds__(256) void ew_head(
    const u16* __restrict__ r16, const u16* __restrict__ k16,
    float* __restrict__ kkout,
    const float* __restrict__ abuf,
    const u16* __restrict__ v0buf, const u16* __restrict__ vsbuf,
    const u16* __restrict__ gbuf,
    const float* __restrict__ y, const float* __restrict__ vfirst,
    const float* __restrict__ kkc, const float* __restrict__ kac,
    const float* __restrict__ rk, const float* __restrict__ lng,
    const float* __restrict__ lnb, u16* __restrict__ z)
{
  const int tid = threadIdx.x;
  const long gh = (long)blockIdx.x * 16 + (tid >> 4);
  const long m = gh >> 5;
  const int h = (int)(gh & 31);
  const int li = tid & 15;
  const int c = h * 64 + li * 4;
  const long off = (m << 11) + c;

  const ushort4v k0p = *(const ushort4v*)(k16 + off);
  const floatx4 av   = *(const floatx4*)(abuf + off);
  const floatx4 kkcv = *(const floatx4*)(kkc + c);
  const floatx4 kacv = *(const floatx4*)(kac + c);
  float k0[4], kf[4], kr[4];
  float ss = 0.f;
#pragma unroll
  for (int i = 0; i < 4; ++i) {
    k0[i] = b2f(k0p[i]);
    kf[i] = k0[i] * (1.f + (av[i] - 1.f) * kacv[i]);
    kr[i] = k0[i] * kkcv[i];
    ss += kr[i] * kr[i];
  }
  const float nrm = sqrtf(wsum16(ss));
  const float rn = 1.f / fmaxf(nrm, 1e-12f);
  floatx4 kkv;
#pragma unroll
  for (int i = 0; i < 4; ++i) kkv[i] = kr[i] * rn;
  *(floatx4*)(kkout + off) = kkv;

  const floatx4 yv = *(const floatx4*)(y + off);
  const float mu = wsum16(yv[0] + yv[1] + yv[2] + yv[3]) * 0.015625f;
  float dy[4], sv2 = 0.f;
#pragma unroll
  for (int i = 0; i < 4; ++i) { dy[i] = yv[i] - mu; sv2 += dy[i] * dy[i]; }
  const float var = wsum16(sv2) * 0.015625f;
  const float rs = rsqrtf(var + 0.00064f);
  const floatx4 lngv = *(const floatx4*)(lng + c);
  const floatx4 lnbv = *(const floatx4*)(lnb + c);
  float yn[4];
#pragma unroll
  for (int i = 0; i < 4; ++i) yn[i] = dy[i] * rs * lngv[i] + lnbv[i];

  const ushort4v rp = *(const ushort4v*)(r16 + off);
  const floatx4 rkv = *(const floatx4*)(rk + c);
  float dd = 0.f;
#pragma unroll
  for (int i = 0; i < 4; ++i) dd += b2f(rp[i]) * kf[i] * rkv[i];
  const float dot = wsum16(dd);

  const ushort4v v0p = *(const ushort4v*)(v0buf + off);
  const ushort4v vsp = *(const ushort4v*)(vsbuf + off);
  const floatx4 vfv  = *(const floatx4*)(vfirst + off);
  const ushort4v gp  = *(const ushort4v*)(gbuf + off);
  ushort4v zo;
#pragma unroll
  for (int i = 0; i < 4; ++i) {
    const float v0v = b2f(v0p[i]);
    const float vv = v0v + (vfv[i] - v0v) * b2f(vsp[i]);
    zo[i] = f2b((yn[i] + dot * vv) * b2f(gp[i]));
  }
  *(ushort4v*)(z + off) = zo;
}

// ---------------- launch ----------------
extern "C" void kernel_launch(void* const* d_in, const int* in_sizes, int n_in,
                              void* d_out, int out_size, void* d_ws, size_t ws_size,
                              hipStream_t stream)
{
  (void)in_sizes; (void)out_size;
  if (n_in < 29) return;
  const int Mrows = 8192;
  const long C = 2048;
  const long MB_ = (long)Mrows * C;

  const float* x   = (const float*)d_in[0];
  const float* vf  = (const float*)d_in[1];
  const float* y   = (const float*)d_in[2];
  const float* x_r = (const float*)d_in[3];
  const float* x_w = (const float*)d_in[4];
  const float* x_k = (const float*)d_in[5];
  const float* x_v = (const float*)d_in[6];
  const float* x_a = (const float*)d_in[7];
  const float* x_g = (const float*)d_in[8];
  const float* w0  = (const float*)d_in[9];
  const float* w1  = (const float*)d_in[10];
  const float* w2  = (const float*)d_in[11];
  const float* a0  = (const float*)d_in[12];
  const float* a1  = (const float*)d_in[13];
  const float* a2  = (const float*)d_in[14];
  const float* v0  = (const float*)d_in[15];
  const float* v1  = (const float*)d_in[16];
  const float* v2  = (const float*)d_in[17];
  const float* g1  = (const float*)d_in[18];
  const float* g2  = (const float*)d_in[19];
  const float* k_k = (const float*)d_in[20];
  const float* k_a = (const float*)d_in[21];
  const float* r_k = (const float*)d_in[22];
  const float* W_r = (const float*)d_in[23];
  const float* W_k = (const float*)d_in[24];
  const float* W_v = (const float*)d_in[25];
  const float* W_o = (const float*)d_in[26];
  const float* lng = (const float*)d_in[27];
  const float* lnb = (const float*)d_in[28];

  float* out_sec = (float*)d_out;
  float* w_sec   = out_sec + MB_;
  float* a_sec   = w_sec + MB_;
  float* kk_sec  = a_sec + MB_;

  u16* k16 = (u16*)out_sec;
  u16* r16 = (u16*)out_sec + MB_;
  u16* Wr16 = (u16*)w_sec;
  u16* Wk16 = Wr16 + C * C;
  u16* Wv16 = Wk16 + C * C;

  u16* p = (u16*)d_ws;
  u16* xr = p;            p += MB_;
  u16* xk = p;            p += MB_;
  u16* xv = p;            p += MB_;
  u16* xw = p;            p += MB_;
  u16* xa = p;            p += MB_;
  u16* xg = p;            p += MB_;
  u16* Wo16 = p;          p += C * C;
  u16* w1T = p;           p += 128 * C;
  u16* a1T = p;           p += 128 * C;
  u16* v1T = p;           p += 128 * C;
  u16* g1T = p;           p += 256 * C;
  u16* w2T = p;           p += C * 128;
  u16* a2T = p;           p += C * 128;
  u16* v2T = p;           p += C * 128;
  u16* g2T = p;           p += C * 256;
  u16* hw  = p;           p += (long)Mrows * 128;
  u16* ha  = p;           p += (long)Mrows * 128;
  u16* hv  = p;           p += (long)Mrows * 128;
  u16* hg  = p;           p += (long)Mrows * 256;
  const size_t need = (size_t)((char*)p - (char*)d_ws);
  if (ws_size < need) return;

  u16* v0buf = xg;
  u16* zbuf  = xk;
  u16* vsbuf = xw;
  u16* gbuf  = xa;

  prep<<<32768, 256, 0, stream>>>(x, x_r, x_k, x_v, x_w, x_a, x_g,
                                  xr, xk, xv, xw, xa, xg,
                                  w1, a1, v1, g1, w2, a2, v2, g2,
                                  w1T, a1T, v1T, g1T, w2T, a2T, v2T, g2T,
                                  W_r, W_k, W_v, W_o, Wr16, Wk16, Wv16, Wo16);
  gemm_s1<<<320, 256, 0, stream>>>(xw, w1T, hw, xa, a1T, ha,
                                   xv, v1T, hv, xg, g1T, hg);
  gemm256<1><<<768, 512, 0, stream>>>(xr, Wr16, r16,
                                      xk, Wk16, k16,
                                      xv, Wv16, v0buf);
  gemm_s2<<<4096, 256, 0, stream>>>(hw, w2T, w_sec, w0,
                                    ha, a2T, a_sec, a0,
                                    hv, v2T, vsbuf, v0,
                                    hg, g2T, gbuf);
  ew_head<<<16384, 256, 0, stream>>>(r16, k16, kk_sec, a_sec, v0buf, vsbuf, gbuf,
                                     y, vf, k_k, k_a, r_k, lng, lnb, zbuf);
  gemm256<0><<<256, 512, 0, stream>>>(zbuf, Wo16, out_sec,
                                      zbuf, Wo16, out_sec,
                                      zbuf, Wo16, out_sec);
}

// Round 22
// 600.925 us; speedup vs baseline: 1.1260x; 1.0729x over previous
//
#include <hip/hip_runtime.h>
#include <math.h>

typedef unsigned short u16;
typedef __attribute__((ext_vector_type(8))) short short8;
typedef __attribute__((ext_vector_type(4))) float floatx4;
typedef __attribute__((ext_vector_type(4))) unsigned short ushort4v;
typedef __attribute__((ext_vector_type(8))) unsigned short ushort8v;

#define DEV static __device__ __forceinline__

DEV u16 f2b(float f) {
  unsigned u = __builtin_bit_cast(unsigned, f);
  u += 0x7fffu + ((u >> 16) & 1u);
  return (u16)(u >> 16);
}
DEV float b2f(u16 h) { return __builtin_bit_cast(float, ((unsigned)h) << 16); }

DEV void gld16(const u16* g, u16* l) {
  __builtin_amdgcn_global_load_lds((__attribute__((address_space(1))) void*)(g),
                                   (__attribute__((address_space(3))) void*)(l), 16, 0, 0);
}

// fast transcendentals: v_exp_f32 / v_rcp_f32 paths (error ~1e-5 rel, ok vs bf16 quantum)
DEV float fexp(float x) { return __expf(x); }
DEV float fsig(float v) { return __builtin_amdgcn_rcpf(1.f + __expf(-v)); }
DEV float ftanh(float v) {
  return 1.f - 2.f * __builtin_amdgcn_rcpf(__expf(2.f * v) + 1.f);
}

// ---------------- K1: merged prep: mixes + LDS-tiled LoRA transposes + weight casts ----------------
__global__ __launch_bounds__(256) void prep(
    const float* __restrict__ x,
    const float* __restrict__ cr, const float* __restrict__ ck,
    const float* __restrict__ cv, const float* __restrict__ cw,
    const float* __restrict__ ca, const float* __restrict__ cg,
    u16* __restrict__ oxr, u16* __restrict__ oxk, u16* __restrict__ oxv,
    u16* __restrict__ oxw, u16* __restrict__ oxa, u16* __restrict__ oxg,
    const float* __restrict__ w1, const float* __restrict__ a1,
    const float* __restrict__ v1, const float* __restrict__ g1,
    const float* __restrict__ w2, const float* __restrict__ a2,
    const float* __restrict__ v2, const float* __restrict__ g2,
    u16* __restrict__ w1T, u16* __restrict__ a1T, u16* __restrict__ v1T,
    u16* __restrict__ g1T, u16* __restrict__ w2T, u16* __restrict__ a2T,
    u16* __restrict__ v2T, u16* __restrict__ g2T,
    const float* __restrict__ Wr, const float* __restrict__ Wk,
    const float* __restrict__ Wv, const float* __restrict__ Wo,
    u16* __restrict__ Wr16, u16* __restrict__ Wk16,
    u16* __restrict__ Wv16, u16* __restrict__ Wo16)
{
  __shared__ float tl[32][33];   // transpose tile (conflict-free pitch)
  const int bid = blockIdx.x;
  const int tid = threadIdx.x;
  if (bid < 8192) {
    const long idx = (long)bid * 256 + tid;
    const long row = idx >> 8;
    const int c8 = (int)(idx & 255) << 3;
    const long off = (row << 11) + c8;
    const floatx4 xa_ = *(const floatx4*)(x + off);
    const floatx4 xb_ = *(const floatx4*)(x + off + 4);
    floatx4 pa = (floatx4)0.f, pb = (floatx4)0.f;
    if ((row & 4095) != 0) {
      pa = *(const floatx4*)(x + off - 2048);
      pb = *(const floatx4*)(x + off - 2044);
    }
    floatx4 da, db;
#pragma unroll
    for (int i = 0; i < 4; ++i) { da[i] = pa[i] - xa_[i]; db[i] = pb[i] - xb_[i]; }
#define EMIT(cp, op) {                                                         \
    const floatx4 c0 = *(const floatx4*)(cp + c8);                             \
    const floatx4 c1 = *(const floatx4*)(cp + c8 + 4);                         \
    ushort8v o;                                                                \
    _Pragma("unroll")                                                          \
    for (int i = 0; i < 4; ++i) {                                              \
      o[i]     = f2b(xa_[i] + da[i] * c0[i]);                                  \
      o[4 + i] = f2b(xb_[i] + db[i] * c1[i]);                                  \
    }                                                                          \
    *(ushort8v*)(op + off) = o; }
    EMIT(cr, oxr); EMIT(ck, oxk); EMIT(cv, oxv);
    EMIT(cw, oxw); EMIT(ca, oxa); EMIT(cg, oxg);
#undef EMIT
    return;
  }
  const int tb = bid - 8192;
  const int by = tb >> 11;
  if (by >= 8) {   // big weight casts, 8 elems/thread
    const long idx = (long)(tb & 2047) * 256 + tid;
    const float* s; u16* d;
    switch (by) {
      case 8:  s = Wr; d = Wr16; break;
      case 9:  s = Wk; d = Wk16; break;
      case 10: s = Wv; d = Wv16; break;
      default: s = Wo; d = Wo16; break;
    }
    const long i = idx * 8;
    const float4 a = *(const float4*)(s + i);
    const float4 b = *(const float4*)(s + i + 4);
    ushort4v lo = { f2b(a.x), f2b(a.y), f2b(a.z), f2b(a.w) };
    ushort4v hi = { f2b(b.x), f2b(b.y), f2b(b.z), f2b(b.w) };
    *(ushort4v*)(d + i) = lo;
    *(ushort4v*)(d + i + 4) = hi;
    return;
  }
  // ---- LDS-tiled transpose (+zero pad): dst[n][k] = src[k][n] ----
  const float* src; u16* dst; int sk, sn, dn, dk;
  switch (by) {
    case 0: src = w1; dst = w1T; sk = 2048; sn = 128; dn = 128;  dk = 2048; break;
    case 1: src = a1; dst = a1T; sk = 2048; sn = 128; dn = 128;  dk = 2048; break;
    case 2: src = v1; dst = v1T; sk = 2048; sn = 64;  dn = 128;  dk = 2048; break;
    case 3: src = g1; dst = g1T; sk = 2048; sn = 224; dn = 256;  dk = 2048; break;
    case 4: src = w2; dst = w2T; sk = 128;  sn = 2048; dn = 2048; dk = 128; break;
    case 5: src = a2; dst = a2T; sk = 128;  sn = 2048; dn = 2048; dk = 128; break;
    case 6: src = v2; dst = v2T; sk = 64;   sn = 2048; dn = 2048; dk = 128; break;
    default:src = g2; dst = g2T; sk = 224;  sn = 2048; dn = 2048; dk = 256; break;
  }
  const int tile_id = tb & 2047;
  const int ntk = dk >> 5, ntn = dn >> 5;
  if (tile_id >= ntk * ntn) return;
  const int tn = tile_id / ntk, tk = tile_id % ntk;
  const int c = tid & 31, rr = tid >> 5;   // 8 rows per pass, 4 passes
#pragma unroll
  for (int i = 0; i < 4; ++i) {
    const int r = rr + i * 8;
    const int k = tk * 32 + r, n = tn * 32 + c;
    float v = 0.f;
    if (k < sk && n < sn) v = src[(long)k * sn + n];   // coalesced along n
    tl[r][c] = v;
  }
  __syncthreads();
#pragma unroll
  for (int i = 0; i < 4; ++i) {
    const int r = rr + i * 8;
    const int n = tn * 32 + r, k = tk * 32 + c;
    dst[(long)n * dk + k] = f2b(tl[c][r]);             // coalesced along k
  }
}

// ---------------- shared 128x128 GEMM body (m97 structure) ----------------
#define GEMM128_BODY(Abase, Bbase, K)                                          \
  floatx4 acc[4][4];                                                           \
  _Pragma("unroll")                                                            \
  for (int i = 0; i < 4; ++i)                                                  \
    _Pragma("unroll")                                                          \
    for (int jq = 0; jq < 4; ++jq) acc[i][jq] = (floatx4)0.f;                  \
  const int nK = (K) >> 6;                                                     \
  for (int kt = 0; kt < nK; ++kt) {                                            \
    const int k0 = kt << 6;                                                    \
    __syncthreads();                                                           \
    _Pragma("unroll")                                                          \
    for (int i = 0; i < 4; ++i) {                                              \
      const int c = i * 256 + tid;                                             \
      const int row = c >> 3;                                                  \
      const int sch = (c & 7) ^ (row & 7);                                     \
      const long goff = (long)row * (K) + k0 + sch * 8;                        \
      const int lbase = (i * 256 + wave * 64) * 8;                             \
      gld16((Abase) + goff, &sA[lbase]);                                       \
      gld16((Bbase) + goff, &sB[lbase]);                                       \
    }                                                                          \
    asm volatile("s_waitcnt vmcnt(0)" ::: "memory");                           \
    __syncthreads();                                                           \
    _Pragma("unroll")                                                          \
    for (int ks = 0; ks < 2; ++ks) {                                           \
      short8 af[4], bfr[4];                                                    \
      _Pragma("unroll")                                                        \
      for (int mi = 0; mi < 4; ++mi) {                                         \
        const int row = wm * 64 + mi * 16 + lrow;                              \
        const int ch = (ks * 4 + lkg) ^ (row & 7);                             \
        af[mi] = *(const short8*)&sA[row * 64 + ch * 8];                       \
      }                                                                        \
      _Pragma("unroll")                                                        \
      for (int ni = 0; ni < 4; ++ni) {                                         \
        const int row = wn * 64 + ni * 16 + lrow;                              \
        const int ch = (ks * 4 + lkg) ^ (row & 7);                             \
        bfr[ni] = *(const short8*)&sB[row * 64 + ch * 8];                      \
      }                                                                        \
      _Pragma("unroll")                                                        \
      for (int mi = 0; mi < 4; ++mi)                                           \
        _Pragma("unroll")                                                      \
        for (int ni = 0; ni < 4; ++ni)                                         \
          acc[mi][ni] = __builtin_amdgcn_mfma_f32_16x16x32_bf16(af[mi], bfr[ni], acc[mi][ni], 0, 0, 0); \
    }                                                                          \
  }

// ---------------- merged LoRA stage-1: 4 jobs, one launch ----------------
__global__ __launch_bounds__(256, 2) void gemm_s1(
    const u16* __restrict__ xw, const u16* __restrict__ w1T, u16* __restrict__ hw,
    const u16* __restrict__ xa, const u16* __restrict__ a1T, u16* __restrict__ ha,
    const u16* __restrict__ xv, const u16* __restrict__ v1T, u16* __restrict__ hv,
    const u16* __restrict__ xg, const u16* __restrict__ g1T, u16* __restrict__ hg)
{
  __shared__ __align__(16) u16 sA[128 * 64];
  __shared__ __align__(16) u16 sB[128 * 64];
  const int bid = blockIdx.x;
  const int jid = (bid < 64) ? 0 : (bid < 128) ? 1 : (bid < 192) ? 2 : 3;
  const u16* A = (jid == 0) ? xw : (jid == 1) ? xa : (jid == 2) ? xv : xg;
  const u16* B = (jid == 0) ? w1T : (jid == 1) ? a1T : (jid == 2) ? v1T : g1T;
  u16* Cv = (jid == 0) ? hw : (jid == 1) ? ha : (jid == 2) ? hv : hg;
  const int N = (jid == 3) ? 256 : 128;
  const int lb = bid - ((jid == 0) ? 0 : (jid == 1) ? 64 : (jid == 2) ? 128 : 192);
  const int tid = threadIdx.x;
  const int wave = tid >> 6, lane = tid & 63;
  const int lrow = lane & 15, lkg = lane >> 4;
  const int wm = wave >> 1, wn = wave & 1;
  const int nbn = N >> 7;
  const int bm = lb / nbn, bn = lb % nbn;
  const u16* Abase = A + (long)bm * 128 * 2048;
  const u16* Bbase = B + (long)bn * 128 * 2048;

  GEMM128_BODY(Abase, Bbase, 2048)

  const int row0 = bm * 128 + wm * 64 + lkg * 4;
  const int col0 = bn * 128 + wn * 64 + lrow;
#pragma unroll
  for (int mi = 0; mi < 4; ++mi)
#pragma unroll
    for (int ni = 0; ni < 4; ++ni) {
      const int col = col0 + ni * 16;
#pragma unroll
      for (int r = 0; r < 4; ++r) {
        const long o = (long)(row0 + mi * 16 + r) * N + col;
        float v = acc[mi][ni][r];
        if (jid == 0) v = ftanh(v);
        else if (jid == 3) v = fsig(v);
        Cv[o] = f2b(v);
      }
    }
}

// ---------------- merged LoRA stage-2: 4 jobs x 1024 blocks ----------------
__global__ __launch_bounds__(256, 2) void gemm_s2(
    const u16* __restrict__ hw, const u16* __restrict__ w2T, float* __restrict__ wsec, const float* __restrict__ w0,
    const u16* __restrict__ ha, const u16* __restrict__ a2T, float* __restrict__ asec, const float* __restrict__ a0,
    const u16* __restrict__ hv, const u16* __restrict__ v2T, u16* __restrict__ vs, const float* __restrict__ v0,
    const u16* __restrict__ hg, const u16* __restrict__ g2T, u16* __restrict__ gb)
{
  __shared__ __align__(16) u16 sA[128 * 64];
  __shared__ __align__(16) u16 sB[128 * 64];
  const int jid = blockIdx.x >> 10;
  const int lb = blockIdx.x & 1023;
  const u16* A = (jid == 0) ? hw : (jid == 1) ? ha : (jid == 2) ? hv : hg;
  const u16* B = (jid == 0) ? w2T : (jid == 1) ? a2T : (jid == 2) ? v2T : g2T;
  const float* bias = (jid == 0) ? w0 : (jid == 1) ? a0 : v0;
  const int K = (jid == 3) ? 256 : 128;
  const int tid = threadIdx.x;
  const int wave = tid >> 6, lane = tid & 63;
  const int lrow = lane & 15, lkg = lane >> 4;
  const int wm = wave >> 1, wn = wave & 1;
  const int bm = lb >> 4, bn = lb & 15;
  const u16* Abase = A + (long)bm * 128 * K;
  const u16* Bbase = B + (long)bn * 128 * K;

  GEMM128_BODY(Abase, Bbase, K)

  const int row0 = bm * 128 + wm * 64 + lkg * 4;
  const int col0 = bn * 128 + wn * 64 + lrow;
#pragma unroll
  for (int mi = 0; mi < 4; ++mi)
#pragma unroll
    for (int ni = 0; ni < 4; ++ni) {
      const int col = col0 + ni * 16;
#pragma unroll
      for (int r = 0; r < 4; ++r) {
        const long o = (long)(row0 + mi * 16 + r) * 2048 + col;
        const float v = acc[mi][ni][r];
        if (jid == 0) {
          const float zz = -(v + bias[col]);
          const float sp = fmaxf(zz, 0.f) + __logf(1.f + fexp(-fabsf(zz)));
          wsec[o] = -sp - 0.5f;
        } else if (jid == 1) {
          asec[o] = fsig(v + bias[col]);
        } else if (jid == 2) {
          vs[o] = f2b(fsig(v + bias[col]));
        } else {
          gb[o] = f2b(v);
        }
      }
    }
}

// ---------------- GEMM 256x256, read-early sections (best measured: 195us, 46-48% MfmaUtil) ----------------
template<int OP>  // 0=f32 out, 1=bf16 out
__global__ __launch_bounds__(512, 2) void gemm256(
    const u16* __restrict__ A0, const u16* __restrict__ B0, void* __restrict__ C0,
    const u16* __restrict__ A1, const u16* __restrict__ B1, void* __restrict__ C1,
    const u16* __restrict__ A2, const u16* __restrict__ B2, void* __restrict__ C2)
{
  __shared__ __align__(16) u16 lds[8 * 8192];
  const int tid = threadIdx.x;
  const int wave = tid >> 6, lane = tid & 63;
  const int lrow = lane & 15, lq = lane >> 4;
  const int wm = wave >> 2, wn = wave & 3;
  const int job = blockIdx.x >> 8;
  const int d = blockIdx.x & 255;
  const int lb = ((d & 7) << 5) | (d >> 3);   // bijective XCD swizzle
  const int bm = lb >> 3, bn = lb & 7;

  const u16* Aj = (job == 0) ? A0 : ((job == 1) ? A1 : A2);
  const u16* Bj = (job == 0) ? B0 : ((job == 1) ? B1 : B2);
  void* Cj      = (job == 0) ? C0 : ((job == 1) ? C1 : C2);

  const u16* __restrict__ Ab = Aj + (long)bm * 256 * 2048;
  const u16* __restrict__ Bb = Bj + (long)bn * 256 * 2048;

  int srco[2], dsto[2];
#pragma unroll
  for (int l = 0; l < 2; ++l) {
    const int c = l * 512 + tid;
    const int row = c >> 2, q = c & 3;
    const int qs = q ^ ((row >> 1) & 3);
    srco[l] = row * 2048 + qs * 8;
    dsto[l] = (l * 512 + wave * 64) * 8;
  }
  int offA[2][4], offB[4];
#pragma unroll
  for (int qm = 0; qm < 2; ++qm)
#pragma unroll
    for (int mi = 0; mi < 4; ++mi) {
      const int r = wm * 128 + qm * 64 + mi * 16 + lrow;
      offA[qm][mi] = r * 32 + (lq ^ ((r >> 1) & 3)) * 8;
    }
#pragma unroll
  for (int ni = 0; ni < 4; ++ni) {
    const int r = wn * 64 + ni * 16 + lrow;
    offB[ni] = r * 32 + (lq ^ ((r >> 1) & 3)) * 8;
  }

  floatx4 acc[8][4];
#pragma unroll
  for (int i = 0; i < 8; ++i)
#pragma unroll
    for (int jq = 0; jq < 4; ++jq) acc[i][jq] = (floatx4)0.f;

#define STAGE(sU, slot) {                                                  \
    const int t_ = (sU) >> 2, j_ = (sU) & 3;                               \
    const u16* base_ = (j_ & 1) ? Bb : Ab;                                 \
    const int kofs_ = t_ * 64 + ((j_ & 2) ? 32 : 0);                       \
    gld16(base_ + srco[0] + kofs_, &lds[(slot) * 8192 + dsto[0]]);         \
    gld16(base_ + srco[1] + kofs_, &lds[(slot) * 8192 + dsto[1]]);         \
  }

#pragma unroll
  for (int s = 0; s < 6; ++s) STAGE(s, s);
  asm volatile("s_waitcnt vmcnt(4)" ::: "memory");
  asm volatile("s_barrier" ::: "memory");

#define SEC(P, sA_, sB_, sS0, sS1)                                             \
  {                                                                            \
    short8 af0[4], af1[4], bfv[4];                                             \
    _Pragma("unroll")                                                          \
    for (int mi = 0; mi < 4; ++mi)                                             \
      af0[mi] = *(const short8*)&lds[(sA_) * 8192 + offA[0][mi]];              \
    _Pragma("unroll")                                                          \
    for (int ni = 0; ni < 4; ++ni)                                             \
      bfv[ni] = *(const short8*)&lds[(sB_) * 8192 + offB[ni]];                 \
    _Pragma("unroll")                                                          \
    for (int mi = 0; mi < 4; ++mi)                                             \
      af1[mi] = *(const short8*)&lds[(sA_) * 8192 + offA[1][mi]];              \
    if ((P) < 61) { asm volatile("s_waitcnt vmcnt(4)" ::: "memory"); }         \
    else          { asm volatile("s_waitcnt vmcnt(0)" ::: "memory"); }         \
    asm volatile("s_barrier" ::: "memory");                                    \
    if ((P) <= 60) {                                                           \
      STAGE(2 * (P) + 6, sS0);                                                 \
      STAGE(2 * (P) + 7, sS1);                                                 \
    }                                                                          \
    _Pragma("unroll")                                                          \
    for (int mi = 0; mi < 4; ++mi)                                             \
      _Pragma("unroll")                                                        \
      for (int ni = 0; ni < 4; ++ni)                                           \
        acc[mi][ni] = __builtin_amdgcn_mfma_f32_16x16x32_bf16(af0[mi], bfv[ni], acc[mi][ni], 0, 0, 0); \
    _Pragma("unroll")                                                          \
    for (int mi = 0; mi < 4; ++mi)                                             \
      _Pragma("unroll")                                                        \
      for (int ni = 0; ni < 4; ++ni)                                           \
        acc[4 + mi][ni] = __builtin_amdgcn_mfma_f32_16x16x32_bf16(af1[mi], bfv[ni], acc[4 + mi][ni], 0, 0, 0); \
  }

  for (int pp = 0; pp < 64; pp += 4) {
    SEC(pp,     0, 1, 6, 7);
    SEC(pp + 1, 2, 3, 0, 1);
    SEC(pp + 2, 4, 5, 2, 3);
    SEC(pp + 3, 6, 7, 4, 5);
  }
#undef SEC
#undef STAGE

  const long row0 = (long)bm * 256 + wm * 128 + lq * 4;
  const int col0 = bn * 256 + wn * 64 + lrow;
#pragma unroll
  for (int mi = 0; mi < 8; ++mi) {
#pragma unroll
    for (int ni = 0; ni < 4; ++ni) {
      const int col = col0 + ni * 16;
#pragma unroll
      for (int r = 0; r < 4; ++r) {
        const long o = (row0 + mi * 16 + r) * 2048 + col;
        const float v = acc[mi][ni][r];
        if constexpr (OP == 0) ((float*)Cj)[o] = v;
        else ((u16*)Cj)[o] = f2b(v);
      }
    }
  }
}

// ---------------- K6: per-head fused epilogue (16 lanes/head, 4 ch/lane) ----------------
DEV float wsum16(float v) {
  v += __shfl_xor(v, 1);  v += __shfl_xor(v, 2);
  v += __shfl_xor(v, 4);  v += __shfl_xor(v, 8);
  return v;
}

__global__ __launch_bounds__(256) void ew_head(
    const u16* __restrict__ r16, const u16* __restrict__ k16,
    float* __restrict__ kkout,
    const float* __restrict__ abuf,
    const u16* __restrict__ v0buf, const u16* __restrict__ vsbuf,
    const u16* __restrict__ gbuf,
    const float* __restrict__ y, const float* __restrict__ vfirst,
    const float* __restrict__ kkc, const float* __restrict__ kac,
    const float* __restrict__ rk, const float* __restrict__ lng,
    const float* __restrict__ lnb, u16* __restrict__ z)
{
  const int tid = threadIdx.x;
  const long gh = (long)blockIdx.x * 16 + (tid >> 4);
  const long m = gh >> 5;
  const int h = (int)(gh & 31);
  const int li = tid & 15;
  const int c = h * 64 + li * 4;
  const long off = (m << 11) + c;

  const ushort4v k0p = *(const ushort4v*)(k16 + off);
  const floatx4 av   = *(const floatx4*)(abuf + off);
  const floatx4 kkcv = *(const floatx4*)(kkc + c);
  const floatx4 kacv = *(const floatx4*)(kac + c);
  float k0[4], kf[4], kr[4];
  float ss = 0.f;
#pragma unroll
  for (int i = 0; i < 4; ++i) {
    k0[i] = b2f(k0p[i]);
    kf[i] = k0[i] * (1.f + (av[i] - 1.f) * kacv[i]);
    kr[i] = k0[i] * kkcv[i];
    ss += kr[i] * kr[i];
  }
  const float nrm = sqrtf(wsum16(ss));
  const float rn = 1.f / fmaxf(nrm, 1e-12f);
  floatx4 kkv;
#pragma unroll
  for (int i = 0; i < 4; ++i) kkv[i] = kr[i] * rn;
  *(floatx4*)(kkout + off) = kkv;

  const floatx4 yv = *(const floatx4*)(y + off);
  const float mu = wsum16(yv[0] + yv[1] + yv[2] + yv[3]) * 0.015625f;
  float dy[4], sv2 = 0.f;
#pragma unroll
  for (int i = 0; i < 4; ++i) { dy[i] = yv[i] - mu; sv2 += dy[i] * dy[i]; }
  const float var = wsum16(sv2) * 0.015625f;
  const float rs = rsqrtf(var + 0.00064f);
  const floatx4 lngv = *(const floatx4*)(lng + c);
  const floatx4 lnbv = *(const floatx4*)(lnb + c);
  float yn[4];
#pragma unroll
  for (int i = 0; i < 4; ++i) yn[i] = dy[i] * rs * lngv[i] + lnbv[i];

  const ushort4v rp = *(const ushort4v*)(r16 + off);
  const floatx4 rkv = *(const floatx4*)(rk + c);
  float dd = 0.f;
#pragma unroll
  for (int i = 0; i < 4; ++i) dd += b2f(rp[i]) * kf[i] * rkv[i];
  const float dot = wsum16(dd);

  const ushort4v v0p = *(const ushort4v*)(v0buf + off);
  const ushort4v vsp = *(const ushort4v*)(vsbuf + off);
  const floatx4 vfv  = *(const floatx4*)(vfirst + off);
  const ushort4v gp  = *(const ushort4v*)(gbuf + off);
  ushort4v zo;
#pragma unroll
  for (int i = 0; i < 4; ++i) {
    const float v0v = b2f(v0p[i]);
    const float vv = v0v + (vfv[i] - v0v) * b2f(vsp[i]);
    zo[i] = f2b((yn[i] + dot * vv) * b2f(gp[i]));
  }
  *(ushort4v*)(z + off) = zo;
}

// ---------------- launch ----------------
extern "C" void kernel_launch(void* const* d_in, const int* in_sizes, int n_in,
                              void* d_out, int out_size, void* d_ws, size_t ws_size,
                              hipStream_t stream)
{
  (void)in_sizes; (void)out_size;
  if (n_in < 29) return;
  const int Mrows = 8192;
  const long C = 2048;
  const long MB_ = (long)Mrows * C;

  const float* x   = (const float*)d_in[0];
  const float* vf  = (const float*)d_in[1];
  const float* y   = (const float*)d_in[2];
  const float* x_r = (const float*)d_in[3];
  const float* x_w = (const float*)d_in[4];
  const float* x_k = (const float*)d_in[5];
  const float* x_v = (const float*)d_in[6];
  const float* x_a = (const float*)d_in[7];
  const float* x_g = (const float*)d_in[8];
  const float* w0  = (const float*)d_in[9];
  const float* w1  = (const float*)d_in[10];
  const float* w2  = (const float*)d_in[11];
  const float* a0  = (const float*)d_in[12];
  const float* a1  = (const float*)d_in[13];
  const float* a2  = (const float*)d_in[14];
  const float* v0  = (const float*)d_in[15];
  const float* v1  = (const float*)d_in[16];
  const float* v2  = (const float*)d_in[17];
  const float* g1  = (const float*)d_in[18];
  const float* g2  = (const float*)d_in[19];
  const float* k_k = (const float*)d_in[20];
  const float* k_a = (const float*)d_in[21];
  const float* r_k = (const float*)d_in[22];
  const float* W_r = (const float*)d_in[23];
  const float* W_k = (const float*)d_in[24];
  const float* W_v = (const float*)d_in[25];
  const float* W_o = (const float*)d_in[26];
  const float* lng = (const float*)d_in[27];
  const float* lnb = (const float*)d_in[28];

  float* out_sec = (float*)d_out;
  float* w_sec   = out_sec + MB_;
  float* a_sec   = w_sec + MB_;
  float* kk_sec  = a_sec + MB_;

  u16* k16 = (u16*)out_sec;
  u16* r16 = (u16*)out_sec + MB_;
  u16* Wr16 = (u16*)w_sec;
  u16* Wk16 = Wr16 + C * C;
  u16* Wv16 = Wk16 + C * C;

  u16* p = (u16*)d_ws;
  u16* xr = p;            p += MB_;
  u16* xk = p;            p += MB_;
  u16* xv = p;            p += MB_;
  u16* xw = p;            p += MB_;
  u16* xa = p;            p += MB_;
  u16* xg = p;            p += MB_;
  u16* Wo16 = p;          p += C * C;
  u16* w1T = p;           p += 128 * C;
  u16* a1T = p;           p += 128 * C;
  u16* v1T = p;           p += 128 * C;
  u16* g1T = p;           p += 256 * C;
  u16* w2T = p;           p += C * 128;
  u16* a2T = p;           p += C * 128;
  u16* v2T = p;           p += C * 128;
  u16* g2T = p;           p += C * 256;
  u16* hw  = p;           p += (long)Mrows * 128;
  u16* ha  = p;           p += (long)Mrows * 128;
  u16* hv  = p;           p += (long)Mrows * 128;
  u16* hg  = p;           p += (long)Mrows * 256;
  const size_t need = (size_t)((char*)p - (char*)d_ws);
  if (ws_size < need) return;

  u16* v0buf = xg;
  u16* zbuf  = xk;
  u16* vsbuf = xw;
  u16* gbuf  = xa;

  prep<<<32768, 256, 0, stream>>>(x, x_r, x_k, x_v, x_w, x_a, x_g,
                                  xr, xk, xv, xw, xa, xg,
                                  w1, a1, v1, g1, w2, a2, v2, g2,
                                  w1T, a1T, v1T, g1T, w2T, a2T, v2T, g2T,
                                  W_r, W_k, W_v, W_o, Wr16, Wk16, Wv16, Wo16);
  gemm_s1<<<320, 256, 0, stream>>>(xw, w1T, hw, xa, a1T, ha,
                                   xv, v1T, hv, xg, g1T, hg);
  gemm256<1><<<768, 512, 0, stream>>>(xr, Wr16, r16,
                                      xk, Wk16, k16,
                                      xv, Wv16, v0buf);
  gemm_s2<<<4096, 256, 0, stream>>>(hw, w2T, w_sec, w0,
                                    ha, a2T, a_sec, a0,
                                    hv, v2T, vsbuf, v0,
                                    hg, g2T, gbuf);
  ew_head<<<16384, 256, 0, stream>>>(r16, k16, kk_sec, a_sec, v0buf, vsbuf, gbuf,
                                     y, vf, k_k, k_a, r_k, lng, lnb, zbuf);
  gemm256<0><<<256, 512, 0, stream>>>(zbuf, Wo16, out_sec,
                                      zbuf, Wo16, out_sec,
                                      zbuf, Wo16, out_sec);
}